// Round 16
// baseline (1604.923 us; speedup 1.0000x reference)
//
#include <hip/hip_runtime.h>
#include <hip/hip_bf16.h>

#define Bb 32
#define Nn 100
#define Cc 256
#define Mm 4096
#define Ff 2048
#define Ll 6
#define Hh 8
#define DH 32
#define KP 100
#define TT (Bb*KP)
#define LNEPS 1e-5f
#define NCH 4
#define SUBK 128

typedef __hip_bfloat16 bf16;
typedef unsigned short ushort_t;
typedef __attribute__((ext_vector_type(8))) short short8v;
typedef __attribute__((ext_vector_type(4))) float f32x4;
typedef __attribute__((ext_vector_type(4))) float f4v;
typedef __attribute__((ext_vector_type(2))) unsigned u2v;

union FragU { uint2 u2[2]; uint4 u4; short8v s8; };

__device__ __forceinline__ float bfu2f(unsigned short u) {
  union { unsigned u32; float f; } cv; cv.u32 = ((unsigned)u) << 16; return cv.f;
}
__device__ __forceinline__ unsigned short f2bf(float f) {
  union { float f; unsigned u; } c; c.f = f;
  unsigned r = c.u + 0x7FFF + ((c.u >> 16) & 1);
  return (unsigned short)(r >> 16);
}
__device__ __forceinline__ unsigned pack2(float a, float b) {
  return (unsigned)f2bf(a) | ((unsigned)f2bf(b) << 16);
}

// ---------------- fused K+V+Q projection GEMM ----------------
// Barrier-free main loop (direct-from-global MFMA fragments). Three grid
// segments: K (bf16 A), V (bf16 A), Q (fp32 A converted in-register,
// output scaled by 1/sqrt(32)). LDS used only for the coalesced epilogue.
__global__ __launch_bounds__(256) void gemm_kv(
    const bf16* __restrict__ Ak, const bf16* __restrict__ Wk,
    const float* __restrict__ bk, bf16* __restrict__ outK,
    const bf16* __restrict__ Avv, const bf16* __restrict__ Wv,
    const float* __restrict__ bv, bf16* __restrict__ outV,
    const float* __restrict__ Aq, const bf16* __restrict__ Wq,
    const float* __restrict__ bq, bf16* __restrict__ outQ)
{
  __shared__ ushort_t Ct[128*136];
  const int nwgK = ((Bb*Mm) >> 7) * 2;     // 512
  const int nwgQ = (TT >> 7) * 2;          // 50
  const int nwg = 2*nwgK + nwgQ;           // 1074
  const int g = blockIdx.x;
  const int xcd = g & 7, lid = g >> 3;
  const int q8 = nwg >> 3, r8 = nwg & 7;
  int wgid = (xcd < r8 ? xcd*(q8+1) : r8*(q8+1) + (xcd - r8)*q8) + lid;
  int seg;
  const bf16* A = nullptr; const bf16* W; const float* bias; bf16* out;
  if (wgid < nwgK)        { seg = 0; A = Ak;  W = Wk; bias = bk; out = outK; }
  else if (wgid < 2*nwgK) { seg = 1; wgid -= nwgK;   A = Avv; W = Wv; bias = bv; out = outV; }
  else                    { seg = 2; wgid -= 2*nwgK; W = Wq; bias = bq; out = outQ; }
  const int ntile = wgid & 1, mtile = wgid >> 1;
  const int bm = mtile << 7, bn = ntile << 7;
  const int tid = threadIdx.x;
  const int w = tid >> 6, lane = tid & 63;
  const int lr = lane & 15, lg = lane >> 4;
  const int wm = w >> 1, wn = w & 1;

  f32x4 acc[4][4] = {};

  if (seg != 2) {
    #pragma unroll 2
    for (int k0 = 0; k0 < Cc; k0 += 32) {
      FragU a[4], b[4];
      #pragma unroll
      for (int mi = 0; mi < 4; ++mi)
        a[mi].u4 = *(const uint4*)(A + (size_t)(bm + wm*64 + mi*16 + lr)*Cc + k0 + lg*8);
      #pragma unroll
      for (int ni = 0; ni < 4; ++ni)
        b[ni].u4 = *(const uint4*)(W + (size_t)(bn + wn*64 + ni*16 + lr)*Cc + k0 + lg*8);
      #pragma unroll
      for (int ni = 0; ni < 4; ++ni)
        #pragma unroll
        for (int mi = 0; mi < 4; ++mi)
          acc[mi][ni] = __builtin_amdgcn_mfma_f32_16x16x32_bf16(a[mi].s8, b[ni].s8,
                                                                acc[mi][ni], 0, 0, 0);
    }
  } else {
    #pragma unroll 2
    for (int k0 = 0; k0 < Cc; k0 += 32) {
      FragU a[4], b[4];
      #pragma unroll
      for (int mi = 0; mi < 4; ++mi) {
        const float* ap = Aq + (size_t)(bm + wm*64 + mi*16 + lr)*Cc + k0 + lg*8;
        float4 f0 = *(const float4*)ap;
        float4 f1 = *(const float4*)(ap + 4);
        a[mi].u4.x = pack2(f0.x, f0.y); a[mi].u4.y = pack2(f0.z, f0.w);
        a[mi].u4.z = pack2(f1.x, f1.y); a[mi].u4.w = pack2(f1.z, f1.w);
      }
      #pragma unroll
      for (int ni = 0; ni < 4; ++ni)
        b[ni].u4 = *(const uint4*)(W + (size_t)(bn + wn*64 + ni*16 + lr)*Cc + k0 + lg*8);
      #pragma unroll
      for (int ni = 0; ni < 4; ++ni)
        #pragma unroll
        for (int mi = 0; mi < 4; ++mi)
          acc[mi][ni] = __builtin_amdgcn_mfma_f32_16x16x32_bf16(a[mi].s8, b[ni].s8,
                                                                acc[mi][ni], 0, 0, 0);
    }
  }

  // coalesced epilogue: C-tile -> LDS -> 16B stores
  const float scale = (seg == 2) ? 0.17677669529663687f : 1.f;
  #pragma unroll
  for (int ni = 0; ni < 4; ++ni) {
    int col = wn*64 + ni*16 + lr;
    float bvv = bias[bn + col];
    #pragma unroll
    for (int mi = 0; mi < 4; ++mi)
      #pragma unroll
      for (int r = 0; r < 4; ++r) {
        int rowl = wm*64 + mi*16 + lg*4 + r;
        Ct[rowl*136 + col] = f2bf((acc[mi][ni][r] + bvv) * scale);
      }
  }
  __syncthreads();
  for (int u = tid; u < 2048; u += 256) {
    int rowl = u >> 4, sub = u & 15;
    uint4 v = *(const uint4*)&Ct[rowl*136 + sub*8];
    int m = bm + rowl;
    int gcol = bn + sub*8;
    int h = gcol >> 5, dd = gcol & 31;
    if (seg != 2) {
      int bb = m >> 12, mm = m & 4095;
      *(uint4*)(out + (((size_t)bb*Hh + h)*Mm + mm)*DH + dd) = v;
    } else {
      int bb = m / KP, qq = m % KP;
      *(uint4*)(out + (((size_t)bb*Hh + h)*KP + qq)*DH + dd) = v;
    }
  }
}

// ---------------- bf16 MFMA GEMM: out = [A(+A2)] @ W^T + bias ----------------
// OM: 0 fp32 row-major; 1 bf16 row-major; 3 bf16 head-major Q scaled.
template<int AT, bool RELU, int OM>
__global__ __launch_bounds__(256) void gemm_mfma(
    const void* __restrict__ Av, const float* __restrict__ A2,
    const bf16* __restrict__ W, const float* __restrict__ bias,
    void* __restrict__ out, int M, int N, int K)
{
  __shared__ ushort_t SM[2*128*72];
  ushort_t* As = SM;            // [128][72]
  ushort_t* Bs = SM + 128*72;   // [128][72]
  const int mt = M >> 7, nt = N >> 7;
  const int nwg = mt * nt;
  const int g = blockIdx.x;
  const int xcd = g & 7, lid = g >> 3;
  const int q8 = nwg >> 3, r8 = nwg & 7;
  int wgid = (xcd < r8 ? xcd*(q8+1) : r8*(q8+1) + (xcd - r8)*q8) + lid;
  const int ntile = wgid % nt, mtile = wgid / nt;
  const int bm = mtile << 7, bn = ntile << 7;
  const int tid = threadIdx.x;
  const int w = tid >> 6, lane = tid & 63;
  const int lr = lane & 15, lg = lane >> 4;
  const int wm = w >> 1, wn = w & 1;
  const float* Af = (const float*)Av;
  const bf16*  Ab = (const bf16*)Av;

  f32x4 acc[4][4] = {};

  for (int k0 = 0; k0 < K; k0 += 64) {
    __syncthreads();
    #pragma unroll
    for (int i = 0; i < 4; ++i) {
      int linear = i*256 + tid;
      int row = linear >> 3, c8 = linear & 7;
      uint4 packed;
      if (AT == 0) {
        const float* ap = Af + (size_t)(bm+row)*K + k0 + c8*8;
        float4 f0 = *(const float4*)ap;
        float4 f1 = *(const float4*)(ap+4);
        if (A2) {
          const float* ap2 = A2 + (size_t)(bm+row)*K + k0 + c8*8;
          float4 g0 = *(const float4*)ap2;
          float4 g1 = *(const float4*)(ap2+4);
          f0.x += g0.x; f0.y += g0.y; f0.z += g0.z; f0.w += g0.w;
          f1.x += g1.x; f1.y += g1.y; f1.z += g1.z; f1.w += g1.w;
        }
        packed.x = pack2(f0.x, f0.y); packed.y = pack2(f0.z, f0.w);
        packed.z = pack2(f1.x, f1.y); packed.w = pack2(f1.z, f1.w);
      } else {
        packed = *(const uint4*)(Ab + (size_t)(bm+row)*K + k0 + c8*8);
      }
      *(uint4*)&As[row*72 + c8*8] = packed;
      uint4 wb = *(const uint4*)(W + (size_t)(bn+row)*K + k0 + c8*8);
      *(uint4*)&Bs[row*72 + c8*8] = wb;
    }
    __syncthreads();
    #pragma unroll
    for (int kk = 0; kk < 64; kk += 32) {
      FragU a[4];
      #pragma unroll
      for (int mi = 0; mi < 4; ++mi)
        a[mi].u4 = *(const uint4*)&As[(wm*64 + mi*16 + lr)*72 + kk + lg*8];
      #pragma unroll
      for (int ni = 0; ni < 4; ++ni) {
        FragU bfr;
        bfr.u4 = *(const uint4*)&Bs[(wn*64 + ni*16 + lr)*72 + kk + lg*8];
        #pragma unroll
        for (int mi = 0; mi < 4; ++mi)
          acc[mi][ni] = __builtin_amdgcn_mfma_f32_16x16x32_bf16(a[mi].s8, bfr.s8,
                                                                acc[mi][ni], 0, 0, 0);
      }
    }
  }

  #pragma unroll
  for (int ni = 0; ni < 4; ++ni) {
    int col = bn + wn*64 + ni*16 + lr;
    float bv = bias ? bias[col] : 0.f;
    #pragma unroll
    for (int mi = 0; mi < 4; ++mi) {
      #pragma unroll
      for (int r = 0; r < 4; ++r) {
        int m = bm + wm*64 + mi*16 + lg*4 + r;
        float v = acc[mi][ni][r] + bv;
        if (RELU) v = fmaxf(v, 0.f);
        if (OM == 0) {
          ((float*)out)[(size_t)m*N + col] = v;
        } else if (OM == 1) {
          ((bf16*)out)[(size_t)m*N + col] = __float2bfloat16(v);
        } else {
          int bb = m / KP, qq = m % KP;
          int h = col >> 5, dd = col & 31;
          ((bf16*)out)[(((size_t)bb*Hh + h)*KP + qq)*DH + dd] =
              __float2bfloat16(v * 0.17677669529663687f);
        }
      }
    }
  }
}

// ------------- GEMM + bias + residual + LayerNorm fused (N=256 fixed) -------------
// 16x256 tile, 512 thr (8 waves, each 16x32). AT: 0 fp32 A, 1 bf16 A,
// 2 = cross-attn combine: A element = combined flash-decode output (part/ml).
template<int AT>
__global__ __launch_bounds__(512) void gemm_ln(
    const void* __restrict__ Av, const bf16* __restrict__ W,
    const float* __restrict__ bias, const float* __restrict__ resid,
    const float* __restrict__ gamma, const float* __restrict__ beta,
    float* __restrict__ out, int M, int K,
    const bf16* __restrict__ part, const float2* __restrict__ ml)
{
  __shared__ ushort_t As[16][72];
  __shared__ ushort_t Bs[256][72];
  __shared__ float redS[16][8];
  __shared__ float redQ[16][8];
  const int bm = blockIdx.x * 16;
  const int tid = threadIdx.x;
  const int w = tid >> 6, lane = tid & 63;
  const int lr = lane & 15, lg = lane >> 4;
  const float* Af = (const float*)Av;
  const bf16*  Ab = (const bf16*)Av;
  f32x4 acc[2] = {};

  for (int k0 = 0; k0 < K; k0 += 64) {
    __syncthreads();
    if (tid < 128) {
      int row = tid >> 3, c8 = tid & 7;
      uint4 packed;
      if (AT == 0) {
        const float* ap = Af + (size_t)(bm+row)*K + k0 + c8*8;
        float4 f0 = *(const float4*)ap;
        float4 f1 = *(const float4*)(ap+4);
        packed.x = pack2(f0.x, f0.y); packed.y = pack2(f0.z, f0.w);
        packed.z = pack2(f1.x, f1.y); packed.w = pack2(f1.z, f1.w);
      } else if (AT == 1) {
        packed = *(const uint4*)(Ab + (size_t)(bm+row)*K + k0 + c8*8);
      } else {
        int t = bm + row;
        int b = t / KP, q = t % KP;
        int ch0 = k0 + c8*8;
        int h = ch0 >> 5, d0 = ch0 & 31;
        int bh = b*Hh + h;
        float2 m0 = ml[((size_t)bh*NCH + 0)*KP + q];
        float2 m1 = ml[((size_t)bh*NCH + 1)*KP + q];
        float2 m2 = ml[((size_t)bh*NCH + 2)*KP + q];
        float2 m3 = ml[((size_t)bh*NCH + 3)*KP + q];
        float mm = fmaxf(fmaxf(m0.x, m1.x), fmaxf(m2.x, m3.x));
        float w0 = __expf(m0.x - mm), w1 = __expf(m1.x - mm);
        float w2 = __expf(m2.x - mm), w3 = __expf(m3.x - mm);
        float invL = 1.f / (m0.y*w0 + m1.y*w1 + m2.y*w2 + m3.y*w3);
        float o[8] = {};
        float wc[NCH] = { w0, w1, w2, w3 };
        #pragma unroll
        for (int c = 0; c < NCH; ++c) {
          uint4 pv = *(const uint4*)(part + (((size_t)bh*NCH + c)*KP + q)*DH + d0);
          const ushort_t* pe = (const ushort_t*)&pv;
          #pragma unroll
          for (int e = 0; e < 8; ++e) o[e] += wc[c] * bfu2f(pe[e]);
        }
        packed.x = pack2(o[0]*invL, o[1]*invL);
        packed.y = pack2(o[2]*invL, o[3]*invL);
        packed.z = pack2(o[4]*invL, o[5]*invL);
        packed.w = pack2(o[6]*invL, o[7]*invL);
      }
      *(uint4*)&As[row][c8*8] = packed;
    }
    #pragma unroll
    for (int i = 0; i < 4; ++i) {
      int linear = i*512 + tid;
      int row = linear >> 3, c8 = linear & 7;
      *(uint4*)&Bs[row][c8*8] = *(const uint4*)(W + (size_t)row*K + k0 + c8*8);
    }
    __syncthreads();
    #pragma unroll
    for (int kk = 0; kk < 64; kk += 32) {
      FragU a;
      a.u4 = *(const uint4*)&As[lr][kk + lg*8];
      #pragma unroll
      for (int ni = 0; ni < 2; ++ni) {
        FragU bfr;
        bfr.u4 = *(const uint4*)&Bs[w*32 + ni*16 + lr][kk + lg*8];
        acc[ni] = __builtin_amdgcn_mfma_f32_16x16x32_bf16(a.s8, bfr.s8, acc[ni], 0, 0, 0);
      }
    }
  }

  float x[2][4];
  #pragma unroll
  for (int r = 0; r < 4; ++r) {
    int row = bm + lg*4 + r;
    float s = 0.f, sq = 0.f;
    #pragma unroll
    for (int ni = 0; ni < 2; ++ni) {
      int col = w*32 + ni*16 + lr;
      float v = acc[ni][r] + bias[col] + resid[(size_t)row*Cc + col];
      x[ni][r] = v;
      s += v; sq += v*v;
    }
    #pragma unroll
    for (int m2 = 1; m2 < 16; m2 <<= 1) { s += __shfl_xor(s, m2); sq += __shfl_xor(sq, m2); }
    if (lr == 0) { redS[lg*4 + r][w] = s; redQ[lg*4 + r][w] = sq; }
  }
  __syncthreads();
  #pragma unroll
  for (int r = 0; r < 4; ++r) {
    int lrow = lg*4 + r;
    float ss = 0.f, sq = 0.f;
    #pragma unroll
    for (int j = 0; j < 8; ++j) { ss += redS[lrow][j]; sq += redQ[lrow][j]; }
    float mean = ss * (1.f/Cc);
    float var = sq * (1.f/Cc) - mean*mean;
    float inv = rsqrtf(var + LNEPS);
    #pragma unroll
    for (int ni = 0; ni < 2; ++ni) {
      int col = w*32 + ni*16 + lr;
      out[(size_t)(bm+lrow)*Cc + col] = (x[ni][r] - mean)*inv*gamma[col] + beta[col];
    }
  }
}

// ---- all weight fp32->bf16 conversions in one dispatch ----
#define NSEG 9
struct CvtDesc {
  const float* src[NSEG];
  bf16* dst[NSEG];
  int n4[NSEG];
  int total4;
};
__global__ __launch_bounds__(256) void cvt_multi(CvtDesc d) {
  int stride = gridDim.x * blockDim.x;
  for (int i = blockIdx.x*256 + threadIdx.x; i < d.total4; i += stride) {
    int seg = 0, off = i;
    while (off >= d.n4[seg]) { off -= d.n4[seg]; ++seg; }
    float4 f = *(const float4*)(d.src[seg] + (size_t)off*4);
    uint2 p; p.x = pack2(f.x, f.y); p.y = pack2(f.z, f.w);
    *(uint2*)(d.dst[seg] + (size_t)off*4) = p;
  }
}

// one-time pack: kb = bf16(mem + mem_pos), vb = bf16(mem). Non-temporal.
__global__ __launch_bounds__(256) void prep_mem(const f4v* __restrict__ mem4,
                                                const f4v* __restrict__ pos4,
                                                u2v* __restrict__ kb2,
                                                u2v* __restrict__ vb2) {
  int i = blockIdx.x*256 + threadIdx.x;
  const int stride = 8192*256;
  #pragma unroll
  for (int t = 0; t < 4; ++t) {
    int j = i + t*stride;
    f4v a = __builtin_nontemporal_load(&mem4[j]);
    f4v p = __builtin_nontemporal_load(&pos4[j]);
    u2v vv, kv;
    vv.x = pack2(a.x, a.y); vv.y = pack2(a.z, a.w);
    kv.x = pack2(a.x + p.x, a.y + p.y); kv.y = pack2(a.z + p.z, a.w + p.w);
    __builtin_nontemporal_store(vv, &vb2[j]);
    __builtin_nontemporal_store(kv, &kb2[j]);
  }
}

// ---------------- fp32 GEMM (front-end only), optional z-paired ----------------
template<bool RELU>
__global__ __launch_bounds__(256) void gemm_nt(
    const float* __restrict__ A0, const float* __restrict__ W0,
    const float* __restrict__ b0, float* __restrict__ o0,
    const float* __restrict__ A1, const float* __restrict__ W1,
    const float* __restrict__ b1, float* __restrict__ o1,
    int M, int N, int K)
{
  const float* A = blockIdx.z ? A1 : A0;
  const float* Wt = blockIdx.z ? W1 : W0;
  const float* bias = blockIdx.z ? b1 : b0;
  float* out = blockIdx.z ? o1 : o0;
  __shared__ float As[16][68];
  __shared__ float Ws[16][68];
  const int bm = blockIdx.y * 64, bn = blockIdx.x * 64;
  const int tid = threadIdx.x;
  const int kk = tid & 15, rr = tid >> 4;
  const int tx = tid & 15, ty = tid >> 4;
  float acc[4][4] = {};
  for (int k0 = 0; k0 < K; k0 += 16) {
    #pragma unroll
    for (int p = 0; p < 4; ++p) {
      int m = rr + p*16;
      int row = bm + m;
      float av = 0.f, wv = 0.f;
      bool kin = (k0 + kk) < K;
      if (row < M && kin) av = A[(size_t)row * K + k0 + kk];
      int wrow = bn + m;
      if (wrow < N && kin) wv = Wt[(size_t)wrow * K + k0 + kk];
      As[kk][m] = av;
      Ws[kk][m] = wv;
    }
    __syncthreads();
    #pragma unroll
    for (int q = 0; q < 16; ++q) {
      float a[4], w[4];
      #pragma unroll
      for (int i = 0; i < 4; ++i) a[i] = As[q][ty*4 + i];
      #pragma unroll
      for (int j = 0; j < 4; ++j) w[j] = Ws[q][tx*4 + j];
      #pragma unroll
      for (int i = 0; i < 4; ++i)
        #pragma unroll
        for (int j = 0; j < 4; ++j) acc[i][j] += a[i] * w[j];
    }
    __syncthreads();
  }
  #pragma unroll
  for (int i = 0; i < 4; ++i) {
    int row = bm + ty*4 + i;
    if (row >= M) continue;
    #pragma unroll
    for (int j = 0; j < 4; ++j) {
      int col = bn + tx*4 + j;
      if (col >= N) continue;
      float v = acc[i][j];
      if (bias) v += bias[col];
      if (RELU) v = v > 0.f ? v : 0.f;
      out[(size_t)row*N + col] = v;
    }
  }
}

// ---------------- small kernels ----------------
__global__ void split_subobj(const float* __restrict__ hs,
                             float* __restrict__ subf, float* __restrict__ objf) {
  int i = blockIdx.x*256 + threadIdx.x;
  if (i >= Bb*Nn*Cc) return;
  int c = i % Cc, n = (i / Cc) % Nn, b = i / (Cc*Nn);
  subf[i] = hs[((size_t)b*2*Nn + 2*n    )*Cc + c];
  objf[i] = hs[((size_t)b*2*Nn + 2*n + 1)*Cc + c];
}

__global__ __launch_bounds__(256) void l2norm_kernel(float* __restrict__ x) {
  int t = blockIdx.x, c = threadIdx.x;
  float v = x[(size_t)t*Cc + c];
  __shared__ float red[256];
  red[c] = v*v; __syncthreads();
  for (int s = 128; s > 0; s >>= 1) { if (c < s) red[c] += red[c+s]; __syncthreads(); }
  float scale = 1.f / (sqrtf(red[0]) + 1e-6f);
  x[(size_t)t*Cc + c] = v * scale;
}

__global__ __launch_bounds__(128) void importance_kernel(const float* __restrict__ se,
                                                         const float* __restrict__ oe,
                                                         float* __restrict__ imp) {
  int b = blockIdx.x / Nn, n = blockIdx.x % Nn;
  int m = threadIdx.x;
  if (m >= Nn) return;
  const float* s = se + ((size_t)b*Nn + n)*Cc;
  const float* o = oe + ((size_t)b*Nn + m)*Cc;
  float acc = 0.f;
  for (int c = 0; c < Cc; ++c) acc += s[c] * o[c];
  imp[((size_t)b*Nn + n)*Nn + m] = acc;
}

// ---------------- exact top-k via radix select + bitonic sort ----------------
__global__ __launch_bounds__(1024) void topk_kernel(const float* __restrict__ imp,
                                                    int* __restrict__ idx_out) {
  __shared__ unsigned mu[Nn*Nn];
  __shared__ unsigned hist[256];
  __shared__ unsigned prefix;
  __shared__ int remK;
  __shared__ unsigned long long keys[128];
  __shared__ unsigned tiebuf[256];
  __shared__ unsigned cnt_gt, cnt_tie;
  const int b = blockIdx.x, tid = threadIdx.x;
  const int NN = Nn*Nn;

  for (int i = tid; i < NN; i += 1024) {
    unsigned u = __float_as_uint(imp[(size_t)b*NN + i]);
    mu[i] = (u & 0x80000000u) ? ~u : (u | 0x80000000u);
  }
  if (tid == 0) { prefix = 0u; remK = KP; cnt_gt = 0u; cnt_tie = 0u; }
  __syncthreads();

  for (int shift = 24; shift >= 0; shift -= 8) {
    if (tid < 256) hist[tid] = 0u;
    __syncthreads();
    unsigned pmask = (shift == 24) ? 0u : (0xFFFFFFFFu << (shift + 8));
    unsigned pref = prefix;
    for (int i = tid; i < NN; i += 1024) {
      unsigned v = mu[i];
      if ((v & pmask) == pref) atomicAdd(&hist[(v >> shift) & 0xFFu], 1u);
    }
    __syncthreads();
    if (tid == 0) {
      int rk = remK;
      unsigned sel = 0u;
      for (int bin = 255; bin >= 0; --bin) {
        int c = (int)hist[bin];
        if (c >= rk) { sel = (unsigned)bin; break; }
        rk -= c;
      }
      remK = rk;
      prefix = pref | (sel << shift);
    }
    __syncthreads();
  }

  const unsigned T = prefix;
  const int need = remK;

  for (int i = tid; i < NN; i += 1024) {
    unsigned v = mu[i];
    if (v > T) {
      unsigned p = atomicAdd(&cnt_gt, 1u);
      keys[p] = ((unsigned long long)(~v) << 32) | (unsigned)i;
    } else if (v == T) {
      unsigned p = atomicAdd(&cnt_tie, 1u);
      if (p < 256u) tiebuf[p] = (unsigned)i;
    }
  }
  __syncthreads();
  const unsigned ngt = cnt_gt;
  const unsigned nt_ = cnt_tie < 256u ? cnt_tie : 256u;

  for (int i = tid; i < 256; i += 1024) if (i >= (int)nt_) tiebuf[i] = 0xFFFFFFFFu;
  __syncthreads();
  for (int ksz = 2; ksz <= 256; ksz <<= 1) {
    for (int st = ksz >> 1; st > 0; st >>= 1) {
      if (tid < 128) {
        int i = ((tid & ~(st-1)) << 1) | (tid & (st-1));
        int j = i | st;
        bool up = ((i & ksz) == 0);
        unsigned a = tiebuf[i], c = tiebuf[j];
        if ((a > c) == up) { tiebuf[i] = c; tiebuf[j] = a; }
      }
      __syncthreads();
    }
  }
  for (int t = tid; t < need; t += 1024)
    keys[ngt + t] = ((unsigned long long)(~T) << 32) | tiebuf[t];
  for (int i = tid; i < 128; i += 1024)
    if (i >= KP) keys[i] = 0xFFFFFFFFFFFFFFFFull;
  __syncthreads();

  for (int ksz = 2; ksz <= 128; ksz <<= 1) {
    for (int st = ksz >> 1; st > 0; st >>= 1) {
      if (tid < 64) {
        int i = ((tid & ~(st-1)) << 1) | (tid & (st-1));
        int j = i | st;
        bool up = ((i & ksz) == 0);
        unsigned long long a = keys[i], c = keys[j];
        if ((a > c) == up) { keys[i] = c; keys[j] = a; }
      }
      __syncthreads();
    }
  }
  if (tid < KP) idx_out[b*KP + tid] = (int)(keys[tid] & 0xFFFFFFFFu);
}

__global__ __launch_bounds__(256) void gather_pair(const float* __restrict__ subf,
                                                   const float* __restrict__ objf,
                                                   const int* __restrict__ idx,
                                                   float* __restrict__ pc) {
  int bk = blockIdx.x;
  int b = bk / KP;
  int id = idx[bk];
  int spos = id / Nn, opos = id % Nn;
  const float* s = subf + ((size_t)b*Nn + spos)*Cc;
  const float* o = objf + ((size_t)b*Nn + opos)*Cc;
  float* dst = pc + (size_t)bk * (2*Cc);
  for (int c = threadIdx.x; c < Cc; c += 256) { dst[c] = s[c]; dst[Cc + c] = o[c]; }
}

__global__ void boxes_cat_kernel(const float* __restrict__ sb, const float* __restrict__ ob,
                                 float* __restrict__ out) {
  int i = blockIdx.x*256 + threadIdx.x;
  if (i >= TT*8) return;
  int c = i & 7, bk = i >> 3;
  out[i] = (c < 4) ? sb[bk*4 + c] : ob[bk*4 + (c - 4)];
}

// ---------------- self-attention: 100 keys, one tile (bf16 qkv) ----------------
__global__ __launch_bounds__(512) void attn_sa(const bf16* __restrict__ qkv,
                                               float* __restrict__ out) {
  __shared__ float Kt[128][36];
  __shared__ float Vt[128][36];
  __shared__ float Qs[KP][DH];
  __shared__ float Ps[8][128];
  int bh = blockIdx.x; int b = bh >> 3, h = bh & 7;
  int tid = threadIdx.x;
  const float scale = 0.17677669529663687f;
  const size_t base = (size_t)b * KP * (3*Cc);
  for (int i = tid; i < KP*DH; i += 512) {
    int q = i >> 5, d = i & 31;
    Qs[q][d] = __bfloat162float(qkv[base + (size_t)q*(3*Cc) + h*DH + d]) * scale;
  }
  {
    int j = tid >> 2, qc = tid & 3;
    float kf[8], vf[8];
    if (j < KP) {
      uint4 kraw = *(const uint4*)(qkv + base + (size_t)j*(3*Cc) + Cc   + h*DH + qc*8);
      uint4 vraw = *(const uint4*)(qkv + base + (size_t)j*(3*Cc) + 2*Cc + h*DH + qc*8);
      const ushort_t* ks = (const ushort_t*)&kraw;
      const ushort_t* vs = (const ushort_t*)&vraw;
      #pragma unroll
      for (int e = 0; e < 8; ++e) { kf[e] = bfu2f(ks[e]); vf[e] = bfu2f(vs[e]); }
    } else {
      #pragma unroll
      for (int e = 0; e < 8; ++e) { kf[e] = 0.f; vf[e] = 0.f; }
    }
    ((float4*)Kt[j])[qc*2]   = make_float4(kf[0],kf[1],kf[2],kf[3]);
    ((float4*)Kt[j])[qc*2+1] = make_float4(kf[4],kf[5],kf[6],kf[7]);
    ((float4*)Vt[j])[qc*2]   = make_float4(vf[0],vf[1],vf[2],vf[3]);
    ((float4*)Vt[j])[qc*2+1] = make_float4(vf[4],vf[5],vf[6],vf[7]);
  }
  __syncthreads();
  int w = tid >> 6, lane = tid & 63;
  int d = lane & 31, half = lane >> 5;
  for (int q = w; q < KP; q += 8) {
    float s0 = 0.f, s1 = 0.f;
    #pragma unroll
    for (int c = 0; c < 8; ++c) {
      float4 k0 = ((const float4*)Kt[lane])[c];
      float4 k1 = ((const float4*)Kt[lane+64])[c];
      float4 qv = *(const float4*)&Qs[q][c*4];
      s0 += k0.x*qv.x + k0.y*qv.y + k0.z*qv.z + k0.w*qv.w;
      s1 += k1.x*qv.x + k1.y*qv.y + k1.z*qv.z + k1.w*qv.w;
    }
    if (lane >= KP) s0 = -1e30f;
    if (lane + 64 >= KP) s1 = -1e30f;
    float mx = fmaxf(s0, s1);
    #pragma unroll
    for (int m2 = 32; m2 > 0; m2 >>= 1) mx = fmaxf(mx, __shfl_xor(mx, m2));
    float p0 = (lane < KP)      ? expf(s0 - mx) : 0.f;
    float p1 = (lane + 64 < KP) ? expf(s1 - mx) : 0.f;
    float sm = p0 + p1;
    #pragma unroll
    for (int m2 = 32; m2 > 0; m2 >>= 1) sm += __shfl_xor(sm, m2);
    Ps[w][lane] = p0; Ps[w][lane+64] = p1;
    float pv = 0.f;
    for (int s = 0; s < 64; ++s) {
      int j = half*64 + s;
      pv += Ps[w][j] * Vt[j][d];
    }
    pv += __shfl_xor(pv, 32);
    if (lane < 32) out[((size_t)b*KP + q)*Cc + h*DH + d] = pv / sm;
  }
}

// ---------------- cross-attention: MFMA flash-decode, register-resident P ----------------
__global__ __launch_bounds__(256) void attn_ca_mfma(
    const bf16* __restrict__ qhH,   // [bh][100][32] pre-scaled
    const bf16* __restrict__ khH,   // [bh][4096][32]
    const bf16* __restrict__ vhH,   // [bh][4096][32]
    bf16* __restrict__ part,        // [bh][NCH][100][32]
    float2* __restrict__ ml)        // [bh][NCH][100]
{
  __shared__ unsigned short Vs[32][140];
  const int bx = blockIdx.x;
  const int bh = bx >> 2, ch = bx & 3;
  const int tid = threadIdx.x;
  const int w = tid >> 6, lane = tid & 63;
  const int lr = lane & 15, lg = lane >> 4;
  const int k0base = ch * (Mm / NCH);
  const int qt0 = w, qt1 = w + 4;

  FragU qf[2];
  {
    int r0 = qt0*16 + lr;
    qf[0].u4 = *(const uint4*)(qhH + ((size_t)bh*KP + r0)*DH + lg*8);
    int r1 = qt1*16 + lr;
    if (r1 < KP) qf[1].u4 = *(const uint4*)(qhH + ((size_t)bh*KP + r1)*DH + lg*8);
    else         qf[1].u4 = make_uint4(0u,0u,0u,0u);
  }

  f32x4 acc[2][2] = {};
  float mreg[2] = {-1e30f, -1e30f};
  float lreg[2] = {0.f, 0.f};

  const int srcA = (2*(lg & 1))*16 + lr;
  const int srcB = srcA + 16;
  const bool hi_kt = (lg >> 1) != 0;

  for (int sc = 0; sc < (Mm/NCH)/SUBK; ++sc) {
    const int k0 = k0base + sc*SUBK;
    __syncthreads();
    {
      int p2 = tid & 63, c = tid >> 6;
      uint4 v0 = *(const uint4*)(vhH + ((size_t)bh*Mm + k0 + 2*p2    )*DH + c*8);
      uint4 v1 = *(const uint4*)(vhH + ((size_t)bh*Mm + k0 + 2*p2 + 1)*DH + c*8);
      const unsigned short* a0 = (const unsigned short*)&v0;
      const unsigned short* a1 = (const unsigned short*)&v1;
      #pragma unroll
      for (int e = 0; e < 8; ++e) {
        int d = c*8 + e;
        *(unsigned int*)&Vs[d][2*p2] = (unsigned)a0[e] | ((unsigned)a1[e] << 16);
      }
    }
    FragU kf[8];
    #pragma unroll
    for (int kt = 0; kt < 8; ++kt)
      kf[kt].u4 = *(const uint4*)(khH + ((size_t)bh*Mm + k0 + kt*16 + lr)*DH + lg*8);
    __syncthreads();

    #pragma unroll
    for (int j = 0; j < 2; ++j) {
      f32x4 sv[8];
      __builtin_amdgcn_s_setprio(1);
      #pragma unroll
      for (int kt = 0; kt < 8; ++kt) {
        f32x4 z = {0.f, 0.f, 0.f, 0.f};
        sv[kt] = __builtin_amdgcn_mfma_f32_16x16x32_bf16(kf[kt].s8, qf[j].s8, z, 0, 0, 0);
      }
      __builtin_amdgcn_s_setprio(0);
      float mx = -1e30f;
      #pragma unroll
      for (int kt = 0; kt < 8; ++kt)
        mx = fmaxf(mx, fmaxf(fmaxf(sv[kt][0], sv[kt][1]), fmaxf(sv[kt][2], sv[kt][3])));
      mx = fmaxf(mx, __shfl_xor(mx, 16));
      mx = fmaxf(mx, __shfl_xor(mx, 32));
      float newm = fmaxf(mreg[j], mx);
      float resc = __expf(mreg[j] - newm);
      mreg[j] = newm;
      float psum = 0.f;
      unsigned pl[8], ph[8];
      #pragma unroll
      for (int kt = 0; kt < 8; ++kt) {
        float p0 = __expf(sv[kt][0] - newm);
        float p1 = __expf(sv[kt][1] - newm);
        float p2 = __expf(sv[kt][2] - newm);
        float p3 = __expf(sv[kt][3] - newm);
        psum += (p0 + p1) + (p2 + p3);
        pl[kt] = pack2(p0, p1);
        ph[kt] = pack2(p2, p3);
      }
      psum += __shfl_xor(psum, 16);
      psum += __shfl_xor(psum, 32);
      lreg[j] = lreg[j]*resc + psum;
      #pragma unroll
      for (int dt = 0; dt < 2; ++dt)
        #pragma unroll
        for (int r = 0; r < 4; ++r) acc[j][dt][r] *= resc;

      #pragma unroll
      for (int ks = 0; ks < 4; ++ks) {
        unsigned aA = __shfl(pl[2*ks],   srcA), bA = __shfl(pl[2*ks+1], srcA);
        unsigned aB = __shfl(ph[2*ks],   srcA), bB = __shfl(ph[2*ks+1], srcA);
        unsigned cA = __shfl(pl[2*ks],   srcB), dA = __shfl(pl[2*ks+1], srcB);
        unsigned cB = __shfl(ph[2*ks],   srcB), dB = __shfl(ph[2*ks+1], srcB);
        FragU pf;
        pf.u4.x = hi_kt ? bA : aA;
        pf.u4.y = hi_kt ? bB : aB;
        pf.u4.z = hi_kt ? dA : cA;
        pf.u4.w = hi_kt ? dB : cB;
        __builtin_amdgcn_s_setprio(1);
        #pragma unroll
        for (int dt = 0; dt < 2; ++dt) {
          FragU vf;
          vf.u2[0] = *(const uint2*)&Vs[dt*16 + lr][ks*32 + lg*8];
          vf.u2[1] = *(const uint2*)&Vs[dt*16 + lr][ks*32 + lg*8 + 4];
          acc[j][dt] = __builtin_amdgcn_mfma_f32_16x16x32_bf16(vf.s8, pf.s8,
                                                               acc[j][dt], 0, 0, 0);
        }
        __builtin_amdgcn_s_setprio(0);
      }
    }
  }

  #pragma unroll
  for (int j = 0; j < 2; ++j) {
    int q = (j ? qt1 : qt0)*16 + lr;
    if (q < KP) {
      if (lg == 0) ml[((size_t)bh*NCH + ch)*KP + q] = make_float2(mreg[j], lreg[j]);
      #pragma unroll
      for (int dt = 0; dt < 2; ++dt)
        #pragma unroll
        for (int r = 0; r < 4; ++r) {
          int d = dt*16 + lg*4 + r;
          part[(((size_t)bh*NCH + ch)*KP + q)*DH + d] = __float2bfloat16(acc[j][dt][r]);
        }
    }
  }
}

// ---------------- host ----------------
extern "C" void kernel_launch(void* const* d_in, const int* in_sizes, int n_in,
                              void* d_out, int out_size, void* d_ws, size_t ws_size,
                              hipStream_t stream) {
  auto in = [&](int i) { return (const float*)d_in[i]; };
  const float* hs        = in(0);
  const float* mem       = in(1);
  const float* mem_pos   = in(2);
  const float* sub_boxes = in(3);
  const float* obj_boxes = in(4);
  const float* su_w1 = in(5),  *su_b1 = in(6),  *su_w2 = in(7),  *su_b2 = in(8);
  const float* ou_w1 = in(9),  *ou_b1 = in(10), *ou_w2 = in(11), *ou_b2 = in(12);
  const float* pm_w1 = in(13), *pm_b1 = in(14), *pm_w2 = in(15), *pm_b2 = in(16);
  const float* sp_w1 = in(17), *sp_b1 = in(18), *sp_w2 = in(19), *sp_b2 = in(20);
  const float* sa_in_w = in(21),  *sa_in_b = in(22), *sa_out_w = in(23), *sa_out_b = in(24);
  const float* ca_in_w = in(25),  *ca_in_b = in(26), *ca_out_w = in(27), *ca_out_b = in(28);
  const float* l1_w = in(29), *l1_b = in(30), *l2_w = in(31), *l2_b = in(32);
  const float* n1_g = in(33), *n1_b = in(34), *n2_g = in(35), *n2_b = in(36);
  const float* n3_g = in(37), *n3_b = in(38);

  char* wsp = (char*)d_ws;
  auto alloc = [&](size_t bytes) { char* p = wsp; wsp += (bytes + 255) & ~(size_t)255; return p; };
  bf16* khH = (bf16*)alloc((size_t)Bb*Mm*Cc*2);
  bf16* vhH = (bf16*)alloc((size_t)Bb*Mm*Cc*2);
  bf16* kmem_b = (bf16*)alloc((size_t)Bb*Mm*Cc*2);
  bf16* vmem_b = (bf16*)alloc((size_t)Bb*Mm*Cc*2);
  bf16* qhH = (bf16*)alloc((size_t)TT*Cc*2);
  bf16* part = (bf16*)alloc((size_t)Bb*Hh*NCH*KP*DH*2);
  float2* mlbuf = (float2*)alloc((size_t)Bb*Hh*NCH*KP*8);
  bf16* sawb = (bf16*)alloc((size_t)Ll*3*Cc*Cc*2);
  bf16* cawb = (bf16*)alloc((size_t)Ll*3*Cc*Cc*2);
  bf16* sowb = (bf16*)alloc((size_t)Ll*Cc*Cc*2);
  bf16* cowb = (bf16*)alloc((size_t)Ll*Cc*Cc*2);
  bf16* l1wb = (bf16*)alloc((size_t)Ll*Ff*Cc*2);
  bf16* l2wb = (bf16*)alloc((size_t)Ll*Cc*Ff*2);
  bf16* pm1b = (bf16*)alloc((size_t)Cc*2*Cc*2);
  bf16* pm2b = (bf16*)alloc((size_t)Cc*Cc*2);
  bf16* spw2b = (bf16*)alloc((size_t)Cc*Cc*2);
  float* subf    = (float*)alloc((size_t)Bb*Nn*Cc*4);
  float* objf    = (float*)alloc((size_t)Bb*Nn*Cc*4);
  float* sub_emb = (float*)alloc((size_t)Bb*Nn*Cc*4);
  float* obj_emb = (float*)alloc((size_t)Bb*Nn*Cc*4);   // contiguous after sub_emb
  float* embh    = (float*)alloc((size_t)TT*2*Cc*4);
  float* embh2   = (float*)alloc((size_t)TT*Cc*4);
  float* imp     = (float*)alloc((size_t)Bb*Nn*Nn*4);
  int*   idx     = (int*)  alloc((size_t)Bb*KP*4);
  float* pair_cat= (float*)alloc((size_t)TT*2*Cc*4);
  float* bxc     = (float*)alloc((size_t)TT*8*4);
  float* spb     = (float*)alloc((size_t)TT*Cc*4);
  float* qbuf    = (float*)alloc((size_t)TT*Cc*4);
  bf16*  qkvb    = (bf16*)alloc((size_t)TT*3*Cc*2);
  float* attn_o  = (float*)alloc((size_t)TT*Cc*4);
  bf16*  ffnb    = (bf16*)alloc((size_t)TT*Ff*2);

  {
    CvtDesc d;
    const float* srcs[NSEG] = { sa_in_w, ca_in_w, sa_out_w, ca_out_w, l1_w, l2_w, pm_w1, pm_w2, sp_w2 };
    bf16* dsts[NSEG] = { sawb, cawb, sowb, cowb, l1wb, l2wb, pm1b, pm2b, spw2b };
    size_t ns[NSEG] = { (size_t)Ll*3*Cc*Cc, (size_t)Ll*3*Cc*Cc, (size_t)Ll*Cc*Cc,
                        (size_t)Ll*Cc*Cc, (size_t)Ll*Ff*Cc, (size_t)Ll*Cc*Ff,
                        (size_t)Cc*2*Cc, (size_t)Cc*Cc, (size_t)Cc*Cc };
    int tot = 0;
    for (int i = 0; i < NSEG; ++i) { d.src[i] = srcs[i]; d.dst[i] = dsts[i]; d.n4[i] = (int)(ns[i]/4); tot += d.n4[i]; }
    d.total4 = tot;
    cvt_multi<<<2048, 256, 0, stream>>>(d);
  }
  prep_mem<<<8192, 256, 0, stream>>>((const f4v*)mem, (const f4v*)mem_pos,
                                     (u2v*)kmem_b, (u2v*)vmem_b);

  auto GFP = [&](const float* A0, const float* W0, const float* b0, float* o0,
                 const float* A1, const float* W1, const float* b1, float* o1,
                 int M, int N, int K, bool relu, int zz) {
    dim3 g((N + 63)/64, (M + 63)/64, zz), t(256);
    if (relu) gemm_nt<true ><<<g, t, 0, stream>>>(A0,W0,b0,o0,A1,W1,b1,o1,M,N,K);
    else      gemm_nt<false><<<g, t, 0, stream>>>(A0,W0,b0,o0,A1,W1,b1,o1,M,N,K);
  };

  auto GM = [&](const void* A, const float* A2, const bf16* W, const float* bias,
                void* out, int M, int N, int K, int OM, bool relu) {
    int blocks = (M >> 7) * (N >> 7);
    if (OM == 0) {
      if (relu) gemm_mfma<0,true ,0><<<blocks,256,0,stream>>>(A,A2,W,bias,out,M,N,K);
      else      gemm_mfma<0,false,0><<<blocks,256,0,stream>>>(A,A2,W,bias,out,M,N,K);
    } else if (OM == 1) {
      if (relu) gemm_mfma<0,true ,1><<<blocks,256,0,stream>>>(A,A2,W,bias,out,M,N,K);
      else      gemm_mfma<0,false,1><<<blocks,256,0,stream>>>(A,A2,W,bias,out,M,N,K);
    } else {
      gemm_mfma<0,false,3><<<blocks,256,0,stream>>>(A,A2,W,bias,out,M,N,K);
    }
  };

  // ---- front-end (exact fp32 feeds top-k ordering) ----
  split_subobj<<<(Bb*Nn*Cc + 255)/256, 256, 0, stream>>>(hs, subf, objf);
  GFP(subf, su_w1, su_b1, embh,  objf,  ou_w1, ou_b1, embh2, TT, Cc, Cc, true,  2);
  GFP(embh, su_w2, su_b2, sub_emb, embh2, ou_w2, ou_b2, obj_emb, TT, Cc, Cc, false, 2);
  l2norm_kernel<<<2*TT, 256, 0, stream>>>(sub_emb);   // obj_emb contiguous after sub_emb
  importance_kernel<<<Bb*Nn, 128, 0, stream>>>(sub_emb, obj_emb, imp);
  topk_kernel<<<Bb, 1024, 0, stream>>>(imp, idx);
  gather_pair<<<TT, 256, 0, stream>>>(subf, objf, idx, pair_cat);
  GM(pair_cat, nullptr, pm1b, pm_b1, embh, TT, Cc, 2*Cc, 0, true);
  GM(embh,     nullptr, pm2b, pm_b2, qbuf, TT, Cc, Cc,   0, false);
  boxes_cat_kernel<<<(TT*8 + 255)/256, 256, 0, stream>>>(sub_boxes, obj_boxes, bxc);
  GFP(bxc,  sp_w1, sp_b1, embh, nullptr,nullptr,nullptr,nullptr, TT, Cc, 8,  true,  1);
  GM(embh, nullptr, spw2b, sp_b2, spb, TT, Cc, Cc, 0, false);

  // ---- decoder layers ----
  for (int i = 0; i < Ll; ++i) {
    const bf16* sawL = sawb + (size_t)i*3*Cc*Cc;
    const bf16* cawL = cawb + (size_t)i*3*Cc*Cc;
    const float* sab = sa_in_b + (size_t)i*3*Cc;
    const float* cab = ca_in_b + (size_t)i*3*Cc;

    // self-attention (q_sp = q + sp fused into staging); LN fused into out-proj
    GM(qbuf, spb, sawL, sab, qkvb, TT, 3*Cc, Cc, 1, false);
    attn_sa<<<Bb*Hh, 512, 0, stream>>>(qkvb, attn_o);
    gemm_ln<0><<<TT/16, 512, 0, stream>>>(attn_o, sowb + (size_t)i*Cc*Cc,
        sa_out_b + (size_t)i*Cc, qbuf, n1_g + i*Cc, n1_b + i*Cc, qbuf, TT, Cc,
        nullptr, nullptr);

    // cross-attention: fused K+V+Q projection (barrier-free), flash-decode,
    // combine fused into LN-GEMM
    gemm_kv<<<1074, 256, 0, stream>>>(
        kmem_b, cawL + (size_t)Cc*Cc,   cab + Cc,   khH,
        vmem_b, cawL + (size_t)2*Cc*Cc, cab + 2*Cc, vhH,
        qbuf,   cawL,                   cab,        qhH);
    attn_ca_mfma<<<Bb*Hh*NCH, 256, 0, stream>>>(qhH, khH, vhH, part, mlbuf);
    gemm_ln<2><<<TT/16, 512, 0, stream>>>(nullptr, cowb + (size_t)i*Cc*Cc,
        ca_out_b + (size_t)i*Cc, qbuf, n2_g + i*Cc, n2_b + i*Cc, qbuf, TT, Cc,
        part, mlbuf);

    // FFN (split: bf16 MFMA GEMM + LN-fused second GEMM)
    GM(qbuf, nullptr, l1wb + (size_t)i*Ff*Cc, l1_b + (size_t)i*Ff, ffnb, TT, Ff, Cc, 1, true);
    float* qo = (i == Ll-1) ? (float*)d_out : qbuf;
    gemm_ln<1><<<TT/16, 512, 0, stream>>>(ffnb, l2wb + (size_t)i*Cc*Ff,
        l2_b + (size_t)i*Cc, qbuf, n3_g + i*Cc, n3_b + i*Cc, qo, TT, Ff,
        nullptr, nullptr);
  }
}

// Round 17
// 1594.201 us; speedup vs baseline: 1.0067x; 1.0067x over previous
//
#include <hip/hip_runtime.h>
#include <hip/hip_bf16.h>

#define Bb 32
#define Nn 100
#define Cc 256
#define Mm 4096
#define Ff 2048
#define Ll 6
#define Hh 8
#define DH 32
#define KP 100
#define TT (Bb*KP)
#define LNEPS 1e-5f
#define NCH 8
#define SUBK 128

typedef __hip_bfloat16 bf16;
typedef unsigned short ushort_t;
typedef __attribute__((ext_vector_type(8))) short short8v;
typedef __attribute__((ext_vector_type(4))) float f32x4;
typedef __attribute__((ext_vector_type(4))) float f4v;
typedef __attribute__((ext_vector_type(2))) unsigned u2v;

union FragU { uint2 u2[2]; uint4 u4; short8v s8; };

__device__ __forceinline__ float bfu2f(unsigned short u) {
  union { unsigned u32; float f; } cv; cv.u32 = ((unsigned)u) << 16; return cv.f;
}
__device__ __forceinline__ unsigned short f2bf(float f) {
  union { float f; unsigned u; } c; c.f = f;
  unsigned r = c.u + 0x7FFF + ((c.u >> 16) & 1);
  return (unsigned short)(r >> 16);
}
__device__ __forceinline__ unsigned pack2(float a, float b) {
  return (unsigned)f2bf(a) | ((unsigned)f2bf(b) << 16);
}

// ---------------- fused K+V+Q projection GEMM ----------------
// Barrier-free main loop (direct-from-global MFMA fragments). Three grid
// segments: K (bf16 A), V (bf16 A), Q (fp32 A converted in-register,
// output scaled by 1/sqrt(32)). LDS used only for the coalesced epilogue.
__global__ __launch_bounds__(256) void gemm_kv(
    const bf16* __restrict__ Ak, const bf16* __restrict__ Wk,
    const float* __restrict__ bk, bf16* __restrict__ outK,
    const bf16* __restrict__ Avv, const bf16* __restrict__ Wv,
    const float* __restrict__ bv, bf16* __restrict__ outV,
    const float* __restrict__ Aq, const bf16* __restrict__ Wq,
    const float* __restrict__ bq, bf16* __restrict__ outQ)
{
  __shared__ ushort_t Ct[128*136];
  const int nwgK = ((Bb*Mm) >> 7) * 2;     // 512
  const int nwgQ = (TT >> 7) * 2;          // 50
  const int nwg = 2*nwgK + nwgQ;           // 1074
  const int g = blockIdx.x;
  const int xcd = g & 7, lid = g >> 3;
  const int q8 = nwg >> 3, r8 = nwg & 7;
  int wgid = (xcd < r8 ? xcd*(q8+1) : r8*(q8+1) + (xcd - r8)*q8) + lid;
  int seg;
  const bf16* A = nullptr; const bf16* W; const float* bias; bf16* out;
  if (wgid < nwgK)        { seg = 0; A = Ak;  W = Wk; bias = bk; out = outK; }
  else if (wgid < 2*nwgK) { seg = 1; wgid -= nwgK;   A = Avv; W = Wv; bias = bv; out = outV; }
  else                    { seg = 2; wgid -= 2*nwgK; W = Wq; bias = bq; out = outQ; }
  const int ntile = wgid & 1, mtile = wgid >> 1;
  const int bm = mtile << 7, bn = ntile << 7;
  const int tid = threadIdx.x;
  const int w = tid >> 6, lane = tid & 63;
  const int lr = lane & 15, lg = lane >> 4;
  const int wm = w >> 1, wn = w & 1;

  f32x4 acc[4][4] = {};

  if (seg != 2) {
    #pragma unroll 2
    for (int k0 = 0; k0 < Cc; k0 += 32) {
      FragU a[4], b[4];
      #pragma unroll
      for (int mi = 0; mi < 4; ++mi)
        a[mi].u4 = *(const uint4*)(A + (size_t)(bm + wm*64 + mi*16 + lr)*Cc + k0 + lg*8);
      #pragma unroll
      for (int ni = 0; ni < 4; ++ni)
        b[ni].u4 = *(const uint4*)(W + (size_t)(bn + wn*64 + ni*16 + lr)*Cc + k0 + lg*8);
      #pragma unroll
      for (int ni = 0; ni < 4; ++ni)
        #pragma unroll
        for (int mi = 0; mi < 4; ++mi)
          acc[mi][ni] = __builtin_amdgcn_mfma_f32_16x16x32_bf16(a[mi].s8, b[ni].s8,
                                                                acc[mi][ni], 0, 0, 0);
    }
  } else {
    #pragma unroll 2
    for (int k0 = 0; k0 < Cc; k0 += 32) {
      FragU a[4], b[4];
      #pragma unroll
      for (int mi = 0; mi < 4; ++mi) {
        const float* ap = Aq + (size_t)(bm + wm*64 + mi*16 + lr)*Cc + k0 + lg*8;
        float4 f0 = *(const float4*)ap;
        float4 f1 = *(const float4*)(ap + 4);
        a[mi].u4.x = pack2(f0.x, f0.y); a[mi].u4.y = pack2(f0.z, f0.w);
        a[mi].u4.z = pack2(f1.x, f1.y); a[mi].u4.w = pack2(f1.z, f1.w);
      }
      #pragma unroll
      for (int ni = 0; ni < 4; ++ni)
        b[ni].u4 = *(const uint4*)(W + (size_t)(bn + wn*64 + ni*16 + lr)*Cc + k0 + lg*8);
      #pragma unroll
      for (int ni = 0; ni < 4; ++ni)
        #pragma unroll
        for (int mi = 0; mi < 4; ++mi)
          acc[mi][ni] = __builtin_amdgcn_mfma_f32_16x16x32_bf16(a[mi].s8, b[ni].s8,
                                                                acc[mi][ni], 0, 0, 0);
    }
  }

  // coalesced epilogue: C-tile -> LDS -> 16B stores
  const float scale = (seg == 2) ? 0.17677669529663687f : 1.f;
  #pragma unroll
  for (int ni = 0; ni < 4; ++ni) {
    int col = wn*64 + ni*16 + lr;
    float bvv = bias[bn + col];
    #pragma unroll
    for (int mi = 0; mi < 4; ++mi)
      #pragma unroll
      for (int r = 0; r < 4; ++r) {
        int rowl = wm*64 + mi*16 + lg*4 + r;
        Ct[rowl*136 + col] = f2bf((acc[mi][ni][r] + bvv) * scale);
      }
  }
  __syncthreads();
  for (int u = tid; u < 2048; u += 256) {
    int rowl = u >> 4, sub = u & 15;
    uint4 v = *(const uint4*)&Ct[rowl*136 + sub*8];
    int m = bm + rowl;
    int gcol = bn + sub*8;
    int h = gcol >> 5, dd = gcol & 31;
    if (seg != 2) {
      int bb = m >> 12, mm = m & 4095;
      *(uint4*)(out + (((size_t)bb*Hh + h)*Mm + mm)*DH + dd) = v;
    } else {
      int bb = m / KP, qq = m % KP;
      *(uint4*)(out + (((size_t)bb*Hh + h)*KP + qq)*DH + dd) = v;
    }
  }
}

// ---------------- bf16 MFMA GEMM: out = [A(+A2)] @ W^T + bias ----------------
// OM: 0 fp32 row-major; 1 bf16 row-major; 3 bf16 head-major Q scaled.
template<int AT, bool RELU, int OM>
__global__ __launch_bounds__(256) void gemm_mfma(
    const void* __restrict__ Av, const float* __restrict__ A2,
    const bf16* __restrict__ W, const float* __restrict__ bias,
    void* __restrict__ out, int M, int N, int K)
{
  __shared__ ushort_t SM[2*128*72];
  ushort_t* As = SM;            // [128][72]
  ushort_t* Bs = SM + 128*72;   // [128][72]
  const int mt = M >> 7, nt = N >> 7;
  const int nwg = mt * nt;
  const int g = blockIdx.x;
  const int xcd = g & 7, lid = g >> 3;
  const int q8 = nwg >> 3, r8 = nwg & 7;
  int wgid = (xcd < r8 ? xcd*(q8+1) : r8*(q8+1) + (xcd - r8)*q8) + lid;
  const int ntile = wgid % nt, mtile = wgid / nt;
  const int bm = mtile << 7, bn = ntile << 7;
  const int tid = threadIdx.x;
  const int w = tid >> 6, lane = tid & 63;
  const int lr = lane & 15, lg = lane >> 4;
  const int wm = w >> 1, wn = w & 1;
  const float* Af = (const float*)Av;
  const bf16*  Ab = (const bf16*)Av;

  f32x4 acc[4][4] = {};

  for (int k0 = 0; k0 < K; k0 += 64) {
    __syncthreads();
    #pragma unroll
    for (int i = 0; i < 4; ++i) {
      int linear = i*256 + tid;
      int row = linear >> 3, c8 = linear & 7;
      uint4 packed;
      if (AT == 0) {
        const float* ap = Af + (size_t)(bm+row)*K + k0 + c8*8;
        float4 f0 = *(const float4*)ap;
        float4 f1 = *(const float4*)(ap+4);
        if (A2) {
          const float* ap2 = A2 + (size_t)(bm+row)*K + k0 + c8*8;
          float4 g0 = *(const float4*)ap2;
          float4 g1 = *(const float4*)(ap2+4);
          f0.x += g0.x; f0.y += g0.y; f0.z += g0.z; f0.w += g0.w;
          f1.x += g1.x; f1.y += g1.y; f1.z += g1.z; f1.w += g1.w;
        }
        packed.x = pack2(f0.x, f0.y); packed.y = pack2(f0.z, f0.w);
        packed.z = pack2(f1.x, f1.y); packed.w = pack2(f1.z, f1.w);
      } else {
        packed = *(const uint4*)(Ab + (size_t)(bm+row)*K + k0 + c8*8);
      }
      *(uint4*)&As[row*72 + c8*8] = packed;
      uint4 wb = *(const uint4*)(W + (size_t)(bn+row)*K + k0 + c8*8);
      *(uint4*)&Bs[row*72 + c8*8] = wb;
    }
    __syncthreads();
    #pragma unroll
    for (int kk = 0; kk < 64; kk += 32) {
      FragU a[4];
      #pragma unroll
      for (int mi = 0; mi < 4; ++mi)
        a[mi].u4 = *(const uint4*)&As[(wm*64 + mi*16 + lr)*72 + kk + lg*8];
      #pragma unroll
      for (int ni = 0; ni < 4; ++ni) {
        FragU bfr;
        bfr.u4 = *(const uint4*)&Bs[(wn*64 + ni*16 + lr)*72 + kk + lg*8];
        #pragma unroll
        for (int mi = 0; mi < 4; ++mi)
          acc[mi][ni] = __builtin_amdgcn_mfma_f32_16x16x32_bf16(a[mi].s8, bfr.s8,
                                                                acc[mi][ni], 0, 0, 0);
      }
    }
  }

  #pragma unroll
  for (int ni = 0; ni < 4; ++ni) {
    int col = bn + wn*64 + ni*16 + lr;
    float bv = bias ? bias[col] : 0.f;
    #pragma unroll
    for (int mi = 0; mi < 4; ++mi) {
      #pragma unroll
      for (int r = 0; r < 4; ++r) {
        int m = bm + wm*64 + mi*16 + lg*4 + r;
        float v = acc[mi][ni][r] + bv;
        if (RELU) v = fmaxf(v, 0.f);
        if (OM == 0) {
          ((float*)out)[(size_t)m*N + col] = v;
        } else if (OM == 1) {
          ((bf16*)out)[(size_t)m*N + col] = __float2bfloat16(v);
        } else {
          int bb = m / KP, qq = m % KP;
          int h = col >> 5, dd = col & 31;
          ((bf16*)out)[(((size_t)bb*Hh + h)*KP + qq)*DH + dd] =
              __float2bfloat16(v * 0.17677669529663687f);
        }
      }
    }
  }
}

// ------------- GEMM + bias + residual + LayerNorm fused (N=256 fixed) -------------
// 16x256 tile, 512 thr (8 waves, each 16x32). AT: 0 fp32 A, 1 bf16 A,
// 2 = cross-attn combine: A element = combined flash-decode output (part/ml).
template<int AT>
__global__ __launch_bounds__(512) void gemm_ln(
    const void* __restrict__ Av, const bf16* __restrict__ W,
    const float* __restrict__ bias, const float* __restrict__ resid,
    const float* __restrict__ gamma, const float* __restrict__ beta,
    float* __restrict__ out, int M, int K,
    const bf16* __restrict__ part, const float2* __restrict__ ml)
{
  __shared__ ushort_t As[16][72];
  __shared__ ushort_t Bs[256][72];
  __shared__ float redS[16][8];
  __shared__ float redQ[16][8];
  const int bm = blockIdx.x * 16;
  const int tid = threadIdx.x;
  const int w = tid >> 6, lane = tid & 63;
  const int lr = lane & 15, lg = lane >> 4;
  const float* Af = (const float*)Av;
  const bf16*  Ab = (const bf16*)Av;
  f32x4 acc[2] = {};

  for (int k0 = 0; k0 < K; k0 += 64) {
    __syncthreads();
    if (tid < 128) {
      int row = tid >> 3, c8 = tid & 7;
      uint4 packed;
      if (AT == 0) {
        const float* ap = Af + (size_t)(bm+row)*K + k0 + c8*8;
        float4 f0 = *(const float4*)ap;
        float4 f1 = *(const float4*)(ap+4);
        packed.x = pack2(f0.x, f0.y); packed.y = pack2(f0.z, f0.w);
        packed.z = pack2(f1.x, f1.y); packed.w = pack2(f1.z, f1.w);
      } else if (AT == 1) {
        packed = *(const uint4*)(Ab + (size_t)(bm+row)*K + k0 + c8*8);
      } else {
        int t = bm + row;
        int b = t / KP, q = t % KP;
        int ch0 = k0 + c8*8;
        int h = ch0 >> 5, d0 = ch0 & 31;
        int bh = b*Hh + h;
        float2 mls[NCH];
        float mmax = -1e30f;
        #pragma unroll
        for (int c = 0; c < NCH; ++c) {
          mls[c] = ml[((size_t)bh*NCH + c)*KP + q];
          mmax = fmaxf(mmax, mls[c].x);
        }
        float wc[NCH];
        float L = 0.f;
        #pragma unroll
        for (int c = 0; c < NCH; ++c) {
          wc[c] = __expf(mls[c].x - mmax);
          L += mls[c].y * wc[c];
        }
        float invL = 1.f / L;
        float o[8] = {};
        #pragma unroll
        for (int c = 0; c < NCH; ++c) {
          uint4 pv = *(const uint4*)(part + (((size_t)bh*NCH + c)*KP + q)*DH + d0);
          const ushort_t* pe = (const ushort_t*)&pv;
          #pragma unroll
          for (int e = 0; e < 8; ++e) o[e] += wc[c] * bfu2f(pe[e]);
        }
        packed.x = pack2(o[0]*invL, o[1]*invL);
        packed.y = pack2(o[2]*invL, o[3]*invL);
        packed.z = pack2(o[4]*invL, o[5]*invL);
        packed.w = pack2(o[6]*invL, o[7]*invL);
      }
      *(uint4*)&As[row][c8*8] = packed;
    }
    #pragma unroll
    for (int i = 0; i < 4; ++i) {
      int linear = i*512 + tid;
      int row = linear >> 3, c8 = linear & 7;
      *(uint4*)&Bs[row][c8*8] = *(const uint4*)(W + (size_t)row*K + k0 + c8*8);
    }
    __syncthreads();
    #pragma unroll
    for (int kk = 0; kk < 64; kk += 32) {
      FragU a;
      a.u4 = *(const uint4*)&As[lr][kk + lg*8];
      #pragma unroll
      for (int ni = 0; ni < 2; ++ni) {
        FragU bfr;
        bfr.u4 = *(const uint4*)&Bs[w*32 + ni*16 + lr][kk + lg*8];
        acc[ni] = __builtin_amdgcn_mfma_f32_16x16x32_bf16(a.s8, bfr.s8, acc[ni], 0, 0, 0);
      }
    }
  }

  float x[2][4];
  #pragma unroll
  for (int r = 0; r < 4; ++r) {
    int row = bm + lg*4 + r;
    float s = 0.f, sq = 0.f;
    #pragma unroll
    for (int ni = 0; ni < 2; ++ni) {
      int col = w*32 + ni*16 + lr;
      float v = acc[ni][r] + bias[col] + resid[(size_t)row*Cc + col];
      x[ni][r] = v;
      s += v; sq += v*v;
    }
    #pragma unroll
    for (int m2 = 1; m2 < 16; m2 <<= 1) { s += __shfl_xor(s, m2); sq += __shfl_xor(sq, m2); }
    if (lr == 0) { redS[lg*4 + r][w] = s; redQ[lg*4 + r][w] = sq; }
  }
  __syncthreads();
  #pragma unroll
  for (int r = 0; r < 4; ++r) {
    int lrow = lg*4 + r;
    float ss = 0.f, sq = 0.f;
    #pragma unroll
    for (int j = 0; j < 8; ++j) { ss += redS[lrow][j]; sq += redQ[lrow][j]; }
    float mean = ss * (1.f/Cc);
    float var = sq * (1.f/Cc) - mean*mean;
    float inv = rsqrtf(var + LNEPS);
    #pragma unroll
    for (int ni = 0; ni < 2; ++ni) {
      int col = w*32 + ni*16 + lr;
      out[(size_t)(bm+lrow)*Cc + col] = (x[ni][r] - mean)*inv*gamma[col] + beta[col];
    }
  }
}

// ---- all weight fp32->bf16 conversions in one dispatch ----
#define NSEG 9
struct CvtDesc {
  const float* src[NSEG];
  bf16* dst[NSEG];
  int n4[NSEG];
  int total4;
};
__global__ __launch_bounds__(256) void cvt_multi(CvtDesc d) {
  int stride = gridDim.x * blockDim.x;
  for (int i = blockIdx.x*256 + threadIdx.x; i < d.total4; i += stride) {
    int seg = 0, off = i;
    while (off >= d.n4[seg]) { off -= d.n4[seg]; ++seg; }
    float4 f = *(const float4*)(d.src[seg] + (size_t)off*4);
    uint2 p; p.x = pack2(f.x, f.y); p.y = pack2(f.z, f.w);
    *(uint2*)(d.dst[seg] + (size_t)off*4) = p;
  }
}

// one-time pack: kb = bf16(mem + mem_pos), vb = bf16(mem). Non-temporal.
__global__ __launch_bounds__(256) void prep_mem(const f4v* __restrict__ mem4,
                                                const f4v* __restrict__ pos4,
                                                u2v* __restrict__ kb2,
                                                u2v* __restrict__ vb2) {
  int i = blockIdx.x*256 + threadIdx.x;
  const int stride = 8192*256;
  #pragma unroll
  for (int t = 0; t < 4; ++t) {
    int j = i + t*stride;
    f4v a = __builtin_nontemporal_load(&mem4[j]);
    f4v p = __builtin_nontemporal_load(&pos4[j]);
    u2v vv, kv;
    vv.x = pack2(a.x, a.y); vv.y = pack2(a.z, a.w);
    kv.x = pack2(a.x + p.x, a.y + p.y); kv.y = pack2(a.z + p.z, a.w + p.w);
    __builtin_nontemporal_store(vv, &vb2[j]);
    __builtin_nontemporal_store(kv, &kb2[j]);
  }
}

// ---------------- fp32 GEMM (front-end only), optional z-paired ----------------
template<bool RELU>
__global__ __launch_bounds__(256) void gemm_nt(
    const float* __restrict__ A0, const float* __restrict__ W0,
    const float* __restrict__ b0, float* __restrict__ o0,
    const float* __restrict__ A1, const float* __restrict__ W1,
    const float* __restrict__ b1, float* __restrict__ o1,
    int M, int N, int K)
{
  const float* A = blockIdx.z ? A1 : A0;
  const float* Wt = blockIdx.z ? W1 : W0;
  const float* bias = blockIdx.z ? b1 : b0;
  float* out = blockIdx.z ? o1 : o0;
  __shared__ float As[16][68];
  __shared__ float Ws[16][68];
  const int bm = blockIdx.y * 64, bn = blockIdx.x * 64;
  const int tid = threadIdx.x;
  const int kk = tid & 15, rr = tid >> 4;
  const int tx = tid & 15, ty = tid >> 4;
  float acc[4][4] = {};
  for (int k0 = 0; k0 < K; k0 += 16) {
    #pragma unroll
    for (int p = 0; p < 4; ++p) {
      int m = rr + p*16;
      int row = bm + m;
      float av = 0.f, wv = 0.f;
      bool kin = (k0 + kk) < K;
      if (row < M && kin) av = A[(size_t)row * K + k0 + kk];
      int wrow = bn + m;
      if (wrow < N && kin) wv = Wt[(size_t)wrow * K + k0 + kk];
      As[kk][m] = av;
      Ws[kk][m] = wv;
    }
    __syncthreads();
    #pragma unroll
    for (int q = 0; q < 16; ++q) {
      float a[4], w[4];
      #pragma unroll
      for (int i = 0; i < 4; ++i) a[i] = As[q][ty*4 + i];
      #pragma unroll
      for (int j = 0; j < 4; ++j) w[j] = Ws[q][tx*4 + j];
      #pragma unroll
      for (int i = 0; i < 4; ++i)
        #pragma unroll
        for (int j = 0; j < 4; ++j) acc[i][j] += a[i] * w[j];
    }
    __syncthreads();
  }
  #pragma unroll
  for (int i = 0; i < 4; ++i) {
    int row = bm + ty*4 + i;
    if (row >= M) continue;
    #pragma unroll
    for (int j = 0; j < 4; ++j) {
      int col = bn + tx*4 + j;
      if (col >= N) continue;
      float v = acc[i][j];
      if (bias) v += bias[col];
      if (RELU) v = v > 0.f ? v : 0.f;
      out[(size_t)row*N + col] = v;
    }
  }
}

// ---------------- small kernels ----------------
__global__ void split_subobj(const float* __restrict__ hs,
                             float* __restrict__ subf, float* __restrict__ objf) {
  int i = blockIdx.x*256 + threadIdx.x;
  if (i >= Bb*Nn*Cc) return;
  int c = i % Cc, n = (i / Cc) % Nn, b = i / (Cc*Nn);
  subf[i] = hs[((size_t)b*2*Nn + 2*n    )*Cc + c];
  objf[i] = hs[((size_t)b*2*Nn + 2*n + 1)*Cc + c];
}

__global__ __launch_bounds__(256) void l2norm_kernel(float* __restrict__ x) {
  int t = blockIdx.x, c = threadIdx.x;
  float v = x[(size_t)t*Cc + c];
  __shared__ float red[256];
  red[c] = v*v; __syncthreads();
  for (int s = 128; s > 0; s >>= 1) { if (c < s) red[c] += red[c+s]; __syncthreads(); }
  float scale = 1.f / (sqrtf(red[0]) + 1e-6f);
  x[(size_t)t*Cc + c] = v * scale;
}

__global__ __launch_bounds__(128) void importance_kernel(const float* __restrict__ se,
                                                         const float* __restrict__ oe,
                                                         float* __restrict__ imp) {
  int b = blockIdx.x / Nn, n = blockIdx.x % Nn;
  int m = threadIdx.x;
  if (m >= Nn) return;
  const float* s = se + ((size_t)b*Nn + n)*Cc;
  const float* o = oe + ((size_t)b*Nn + m)*Cc;
  float acc = 0.f;
  for (int c = 0; c < Cc; ++c) acc += s[c] * o[c];
  imp[((size_t)b*Nn + n)*Nn + m] = acc;
}

// ---------------- exact top-k via radix select + bitonic sort ----------------
__global__ __launch_bounds__(1024) void topk_kernel(const float* __restrict__ imp,
                                                    int* __restrict__ idx_out) {
  __shared__ unsigned mu[Nn*Nn];
  __shared__ unsigned hist[256];
  __shared__ unsigned prefix;
  __shared__ int remK;
  __shared__ unsigned long long keys[128];
  __shared__ unsigned tiebuf[256];
  __shared__ unsigned cnt_gt, cnt_tie;
  const int b = blockIdx.x, tid = threadIdx.x;
  const int NN = Nn*Nn;

  for (int i = tid; i < NN; i += 1024) {
    unsigned u = __float_as_uint(imp[(size_t)b*NN + i]);
    mu[i] = (u & 0x80000000u) ? ~u : (u | 0x80000000u);
  }
  if (tid == 0) { prefix = 0u; remK = KP; cnt_gt = 0u; cnt_tie = 0u; }
  __syncthreads();

  for (int shift = 24; shift >= 0; shift -= 8) {
    if (tid < 256) hist[tid] = 0u;
    __syncthreads();
    unsigned pmask = (shift == 24) ? 0u : (0xFFFFFFFFu << (shift + 8));
    unsigned pref = prefix;
    for (int i = tid; i < NN; i += 1024) {
      unsigned v = mu[i];
      if ((v & pmask) == pref) atomicAdd(&hist[(v >> shift) & 0xFFu], 1u);
    }
    __syncthreads();
    if (tid == 0) {
      int rk = remK;
      unsigned sel = 0u;
      for (int bin = 255; bin >= 0; --bin) {
        int c = (int)hist[bin];
        if (c >= rk) { sel = (unsigned)bin; break; }
        rk -= c;
      }
      remK = rk;
      prefix = pref | (sel << shift);
    }
    __syncthreads();
  }

  const unsigned T = prefix;
  const int need = remK;

  for (int i = tid; i < NN; i += 1024) {
    unsigned v = mu[i];
    if (v > T) {
      unsigned p = atomicAdd(&cnt_gt, 1u);
      keys[p] = ((unsigned long long)(~v) << 32) | (unsigned)i;
    } else if (v == T) {
      unsigned p = atomicAdd(&cnt_tie, 1u);
      if (p < 256u) tiebuf[p] = (unsigned)i;
    }
  }
  __syncthreads();
  const unsigned ngt = cnt_gt;
  const unsigned nt_ = cnt_tie < 256u ? cnt_tie : 256u;

  for (int i = tid; i < 256; i += 1024) if (i >= (int)nt_) tiebuf[i] = 0xFFFFFFFFu;
  __syncthreads();
  for (int ksz = 2; ksz <= 256; ksz <<= 1) {
    for (int st = ksz >> 1; st > 0; st >>= 1) {
      if (tid < 128) {
        int i = ((tid & ~(st-1)) << 1) | (tid & (st-1));
        int j = i | st;
        bool up = ((i & ksz) == 0);
        unsigned a = tiebuf[i], c = tiebuf[j];
        if ((a > c) == up) { tiebuf[i] = c; tiebuf[j] = a; }
      }
      __syncthreads();
    }
  }
  for (int t = tid; t < need; t += 1024)
    keys[ngt + t] = ((unsigned long long)(~T) << 32) | tiebuf[t];
  for (int i = tid; i < 128; i += 1024)
    if (i >= KP) keys[i] = 0xFFFFFFFFFFFFFFFFull;
  __syncthreads();

  for (int ksz = 2; ksz <= 128; ksz <<= 1) {
    for (int st = ksz >> 1; st > 0; st >>= 1) {
      if (tid < 64) {
        int i = ((tid & ~(st-1)) << 1) | (tid & (st-1));
        int j = i | st;
        bool up = ((i & ksz) == 0);
        unsigned long long a = keys[i], c = keys[j];
        if ((a > c) == up) { keys[i] = c; keys[j] = a; }
      }
      __syncthreads();
    }
  }
  if (tid < KP) idx_out[b*KP + tid] = (int)(keys[tid] & 0xFFFFFFFFu);
}

__global__ __launch_bounds__(256) void gather_pair(const float* __restrict__ subf,
                                                   const float* __restrict__ objf,
                                                   const int* __restrict__ idx,
                                                   float* __restrict__ pc) {
  int bk = blockIdx.x;
  int b = bk / KP;
  int id = idx[bk];
  int spos = id / Nn, opos = id % Nn;
  const float* s = subf + ((size_t)b*Nn + spos)*Cc;
  const float* o = objf + ((size_t)b*Nn + opos)*Cc;
  float* dst = pc + (size_t)bk * (2*Cc);
  for (int c = threadIdx.x; c < Cc; c += 256) { dst[c] = s[c]; dst[Cc + c] = o[c]; }
}

__global__ void boxes_cat_kernel(const float* __restrict__ sb, const float* __restrict__ ob,
                                 float* __restrict__ out) {
  int i = blockIdx.x*256 + threadIdx.x;
  if (i >= TT*8) return;
  int c = i & 7, bk = i >> 3;
  out[i] = (c < 4) ? sb[bk*4 + c] : ob[bk*4 + (c - 4)];
}

// ---------------- self-attention: 100 keys, one tile (bf16 qkv) ----------------
__global__ __launch_bounds__(512) void attn_sa(const bf16* __restrict__ qkv,
                                               float* __restrict__ out) {
  __shared__ float Kt[128][36];
  __shared__ float Vt[128][36];
  __shared__ float Qs[KP][DH];
  __shared__ float Ps[8][128];
  int bh = blockIdx.x; int b = bh >> 3, h = bh & 7;
  int tid = threadIdx.x;
  const float scale = 0.17677669529663687f;
  const size_t base = (size_t)b * KP * (3*Cc);
  for (int i = tid; i < KP*DH; i += 512) {
    int q = i >> 5, d = i & 31;
    Qs[q][d] = __bfloat162float(qkv[base + (size_t)q*(3*Cc) + h*DH + d]) * scale;
  }
  {
    int j = tid >> 2, qc = tid & 3;
    float kf[8], vf[8];
    if (j < KP) {
      uint4 kraw = *(const uint4*)(qkv + base + (size_t)j*(3*Cc) + Cc   + h*DH + qc*8);
      uint4 vraw = *(const uint4*)(qkv + base + (size_t)j*(3*Cc) + 2*Cc + h*DH + qc*8);
      const ushort_t* ks = (const ushort_t*)&kraw;
      const ushort_t* vs = (const ushort_t*)&vraw;
      #pragma unroll
      for (int e = 0; e < 8; ++e) { kf[e] = bfu2f(ks[e]); vf[e] = bfu2f(vs[e]); }
    } else {
      #pragma unroll
      for (int e = 0; e < 8; ++e) { kf[e] = 0.f; vf[e] = 0.f; }
    }
    ((float4*)Kt[j])[qc*2]   = make_float4(kf[0],kf[1],kf[2],kf[3]);
    ((float4*)Kt[j])[qc*2+1] = make_float4(kf[4],kf[5],kf[6],kf[7]);
    ((float4*)Vt[j])[qc*2]   = make_float4(vf[0],vf[1],vf[2],vf[3]);
    ((float4*)Vt[j])[qc*2+1] = make_float4(vf[4],vf[5],vf[6],vf[7]);
  }
  __syncthreads();
  int w = tid >> 6, lane = tid & 63;
  int d = lane & 31, half = lane >> 5;
  for (int q = w; q < KP; q += 8) {
    float s0 = 0.f, s1 = 0.f;
    #pragma unroll
    for (int c = 0; c < 8; ++c) {
      float4 k0 = ((const float4*)Kt[lane])[c];
      float4 k1 = ((const float4*)Kt[lane+64])[c];
      float4 qv = *(const float4*)&Qs[q][c*4];
      s0 += k0.x*qv.x + k0.y*qv.y + k0.z*qv.z + k0.w*qv.w;
      s1 += k1.x*qv.x + k1.y*qv.y + k1.z*qv.z + k1.w*qv.w;
    }
    if (lane >= KP) s0 = -1e30f;
    if (lane + 64 >= KP) s1 = -1e30f;
    float mx = fmaxf(s0, s1);
    #pragma unroll
    for (int m2 = 32; m2 > 0; m2 >>= 1) mx = fmaxf(mx, __shfl_xor(mx, m2));
    float p0 = (lane < KP)      ? expf(s0 - mx) : 0.f;
    float p1 = (lane + 64 < KP) ? expf(s1 - mx) : 0.f;
    float sm = p0 + p1;
    #pragma unroll
    for (int m2 = 32; m2 > 0; m2 >>= 1) sm += __shfl_xor(sm, m2);
    Ps[w][lane] = p0; Ps[w][lane+64] = p1;
    float pv = 0.f;
    for (int s = 0; s < 64; ++s) {
      int j = half*64 + s;
      pv += Ps[w][j] * Vt[j][d];
    }
    pv += __shfl_xor(pv, 32);
    if (lane < 32) out[((size_t)b*KP + q)*Cc + h*DH + d] = pv / sm;
  }
}

// ---------------- cross-attention: MFMA flash-decode, register-resident P ----------------
__global__ __launch_bounds__(256) void attn_ca_mfma(
    const bf16* __restrict__ qhH,   // [bh][100][32] pre-scaled
    const bf16* __restrict__ khH,   // [bh][4096][32]
    const bf16* __restrict__ vhH,   // [bh][4096][32]
    bf16* __restrict__ part,        // [bh][NCH][100][32]
    float2* __restrict__ ml)        // [bh][NCH][100]
{
  __shared__ unsigned short Vs[32][140];
  const int bx = blockIdx.x;
  const int bh = bx >> 3, ch = bx & 7;
  const int tid = threadIdx.x;
  const int w = tid >> 6, lane = tid & 63;
  const int lr = lane & 15, lg = lane >> 4;
  const int k0base = ch * (Mm / NCH);
  const int qt0 = w, qt1 = w + 4;

  FragU qf[2];
  {
    int r0 = qt0*16 + lr;
    qf[0].u4 = *(const uint4*)(qhH + ((size_t)bh*KP + r0)*DH + lg*8);
    int r1 = qt1*16 + lr;
    if (r1 < KP) qf[1].u4 = *(const uint4*)(qhH + ((size_t)bh*KP + r1)*DH + lg*8);
    else         qf[1].u4 = make_uint4(0u,0u,0u,0u);
  }

  f32x4 acc[2][2] = {};
  float mreg[2] = {-1e30f, -1e30f};
  float lreg[2] = {0.f, 0.f};

  const int srcA = (2*(lg & 1))*16 + lr;
  const int srcB = srcA + 16;
  const bool hi_kt = (lg >> 1) != 0;

  for (int sc = 0; sc < (Mm/NCH)/SUBK; ++sc) {
    const int k0 = k0base + sc*SUBK;
    __syncthreads();
    {
      int p2 = tid & 63, c = tid >> 6;
      uint4 v0 = *(const uint4*)(vhH + ((size_t)bh*Mm + k0 + 2*p2    )*DH + c*8);
      uint4 v1 = *(const uint4*)(vhH + ((size_t)bh*Mm + k0 + 2*p2 + 1)*DH + c*8);
      const unsigned short* a0 = (const unsigned short*)&v0;
      const unsigned short* a1 = (const unsigned short*)&v1;
      #pragma unroll
      for (int e = 0; e < 8; ++e) {
        int d = c*8 + e;
        *(unsigned int*)&Vs[d][2*p2] = (unsigned)a0[e] | ((unsigned)a1[e] << 16);
      }
    }
    FragU kf[8];
    #pragma unroll
    for (int kt = 0; kt < 8; ++kt)
      kf[kt].u4 = *(const uint4*)(khH + ((size_t)bh*Mm + k0 + kt*16 + lr)*DH + lg*8);
    __syncthreads();

    #pragma unroll
    for (int j = 0; j < 2; ++j) {
      f32x4 sv[8];
      __builtin_amdgcn_s_setprio(1);
      #pragma unroll
      for (int kt = 0; kt < 8; ++kt) {
        f32x4 z = {0.f, 0.f, 0.f, 0.f};
        sv[kt] = __builtin_amdgcn_mfma_f32_16x16x32_bf16(kf[kt].s8, qf[j].s8, z, 0, 0, 0);
      }
      __builtin_amdgcn_s_setprio(0);
      float mx = -1e30f;
      #pragma unroll
      for (int kt = 0; kt < 8; ++kt)
        mx = fmaxf(mx, fmaxf(fmaxf(sv[kt][0], sv[kt][1]), fmaxf(sv[kt][2], sv[kt][3])));
      mx = fmaxf(mx, __shfl_xor(mx, 16));
      mx = fmaxf(mx, __shfl_xor(mx, 32));
      float newm = fmaxf(mreg[j], mx);
      float resc = __expf(mreg[j] - newm);
      mreg[j] = newm;
      float psum = 0.f;
      unsigned pl[8], ph[8];
      #pragma unroll
      for (int kt = 0; kt < 8; ++kt) {
        float p0 = __expf(sv[kt][0] - newm);
        float p1 = __expf(sv[kt][1] - newm);
        float p2 = __expf(sv[kt][2] - newm);
        float p3 = __expf(sv[kt][3] - newm);
        psum += (p0 + p1) + (p2 + p3);
        pl[kt] = pack2(p0, p1);
        ph[kt] = pack2(p2, p3);
      }
      psum += __shfl_xor(psum, 16);
      psum += __shfl_xor(psum, 32);
      lreg[j] = lreg[j]*resc + psum;
      #pragma unroll
      for (int dt = 0; dt < 2; ++dt)
        #pragma unroll
        for (int r = 0; r < 4; ++r) acc[j][dt][r] *= resc;

      #pragma unroll
      for (int ks = 0; ks < 4; ++ks) {
        unsigned aA = __shfl(pl[2*ks],   srcA), bA = __shfl(pl[2*ks+1], srcA);
        unsigned aB = __shfl(ph[2*ks],   srcA), bB = __shfl(ph[2*ks+1], srcA);
        unsigned cA = __shfl(pl[2*ks],   srcB), dA = __shfl(pl[2*ks+1], srcB);
        unsigned cB = __shfl(ph[2*ks],   srcB), dB = __shfl(ph[2*ks+1], srcB);
        FragU pf;
        pf.u4.x = hi_kt ? bA : aA;
        pf.u4.y = hi_kt ? bB : aB;
        pf.u4.z = hi_kt ? dA : cA;
        pf.u4.w = hi_kt ? dB : cB;
        __builtin_amdgcn_s_setprio(1);
        #pragma unroll
        for (int dt = 0; dt < 2; ++dt) {
          FragU vf;
          vf.u2[0] = *(const uint2*)&Vs[dt*16 + lr][ks*32 + lg*8];
          vf.u2[1] = *(const uint2*)&Vs[dt*16 + lr][ks*32 + lg*8 + 4];
          acc[j][dt] = __builtin_amdgcn_mfma_f32_16x16x32_bf16(vf.s8, pf.s8,
                                                               acc[j][dt], 0, 0, 0);
        }
        __builtin_amdgcn_s_setprio(0);
      }
    }
  }

  #pragma unroll
  for (int j = 0; j < 2; ++j) {
    int q = (j ? qt1 : qt0)*16 + lr;
    if (q < KP) {
      if (lg == 0) ml[((size_t)bh*NCH + ch)*KP + q] = make_float2(mreg[j], lreg[j]);
      #pragma unroll
      for (int dt = 0; dt < 2; ++dt)
        #pragma unroll
        for (int r = 0; r < 4; ++r) {
          int d = dt*16 + lg*4 + r;
          part[(((size_t)bh*NCH + ch)*KP + q)*DH + d] = __float2bfloat16(acc[j][dt][r]);
        }
    }
  }
}

// ---------------- host ----------------
extern "C" void kernel_launch(void* const* d_in, const int* in_sizes, int n_in,
                              void* d_out, int out_size, void* d_ws, size_t ws_size,
                              hipStream_t stream) {
  auto in = [&](int i) { return (const float*)d_in[i]; };
  const float* hs        = in(0);
  const float* mem       = in(1);
  const float* mem_pos   = in(2);
  const float* sub_boxes = in(3);
  const float* obj_boxes = in(4);
  const float* su_w1 = in(5),  *su_b1 = in(6),  *su_w2 = in(7),  *su_b2 = in(8);
  const float* ou_w1 = in(9),  *ou_b1 = in(10), *ou_w2 = in(11), *ou_b2 = in(12);
  const float* pm_w1 = in(13), *pm_b1 = in(14), *pm_w2 = in(15), *pm_b2 = in(16);
  const float* sp_w1 = in(17), *sp_b1 = in(18), *sp_w2 = in(19), *sp_b2 = in(20);
  const float* sa_in_w = in(21),  *sa_in_b = in(22), *sa_out_w = in(23), *sa_out_b = in(24);
  const float* ca_in_w = in(25),  *ca_in_b = in(26), *ca_out_w = in(27), *ca_out_b = in(28);
  const float* l1_w = in(29), *l1_b = in(30), *l2_w = in(31), *l2_b = in(32);
  const float* n1_g = in(33), *n1_b = in(34), *n2_g = in(35), *n2_b = in(36);
  const float* n3_g = in(37), *n3_b = in(38);

  char* wsp = (char*)d_ws;
  auto alloc = [&](size_t bytes) { char* p = wsp; wsp += (bytes + 255) & ~(size_t)255; return p; };
  bf16* khH = (bf16*)alloc((size_t)Bb*Mm*Cc*2);
  bf16* vhH = (bf16*)alloc((size_t)Bb*Mm*Cc*2);
  bf16* kmem_b = (bf16*)alloc((size_t)Bb*Mm*Cc*2);
  bf16* vmem_b = (bf16*)alloc((size_t)Bb*Mm*Cc*2);
  bf16* qhH = (bf16*)alloc((size_t)TT*Cc*2);
  bf16* part = (bf16*)alloc((size_t)Bb*Hh*NCH*KP*DH*2);
  float2* mlbuf = (float2*)alloc((size_t)Bb*Hh*NCH*KP*8);
  bf16* sawb = (bf16*)alloc((size_t)Ll*3*Cc*Cc*2);
  bf16* cawb = (bf16*)alloc((size_t)Ll*3*Cc*Cc*2);
  bf16* sowb = (bf16*)alloc((size_t)Ll*Cc*Cc*2);
  bf16* cowb = (bf16*)alloc((size_t)Ll*Cc*Cc*2);
  bf16* l1wb = (bf16*)alloc((size_t)Ll*Ff*Cc*2);
  bf16* l2wb = (bf16*)alloc((size_t)Ll*Cc*Ff*2);
  bf16* pm1b = (bf16*)alloc((size_t)Cc*2*Cc*2);
  bf16* pm2b = (bf16*)alloc((size_t)Cc*Cc*2);
  bf16* spw2b = (bf16*)alloc((size_t)Cc*Cc*2);
  float* subf    = (float*)alloc((size_t)Bb*Nn*Cc*4);
  float* objf    = (float*)alloc((size_t)Bb*Nn*Cc*4);
  float* sub_emb = (float*)alloc((size_t)Bb*Nn*Cc*4);
  float* obj_emb = (float*)alloc((size_t)Bb*Nn*Cc*4);   // contiguous after sub_emb
  float* embh    = (float*)alloc((size_t)TT*2*Cc*4);
  float* embh2   = (float*)alloc((size_t)TT*Cc*4);
  float* imp     = (float*)alloc((size_t)Bb*Nn*Nn*4);
  int*   idx     = (int*)  alloc((size_t)Bb*KP*4);
  float* pair_cat= (float*)alloc((size_t)TT*2*Cc*4);
  float* bxc     = (float*)alloc((size_t)TT*8*4);
  float* spb     = (float*)alloc((size_t)TT*Cc*4);
  float* qbuf    = (float*)alloc((size_t)TT*Cc*4);
  bf16*  qkvb    = (bf16*)alloc((size_t)TT*3*Cc*2);
  float* attn_o  = (float*)alloc((size_t)TT*Cc*4);
  bf16*  ffnb    = (bf16*)alloc((size_t)TT*Ff*2);

  {
    CvtDesc d;
    const float* srcs[NSEG] = { sa_in_w, ca_in_w, sa_out_w, ca_out_w, l1_w, l2_w, pm_w1, pm_w2, sp_w2 };
    bf16* dsts[NSEG] = { sawb, cawb, sowb, cowb, l1wb, l2wb, pm1b, pm2b, spw2b };
    size_t ns[NSEG] = { (size_t)Ll*3*Cc*Cc, (size_t)Ll*3*Cc*Cc, (size_t)Ll*Cc*Cc,
                        (size_t)Ll*Cc*Cc, (size_t)Ll*Ff*Cc, (size_t)Ll*Cc*Ff,
                        (size_t)Cc*2*Cc, (size_t)Cc*Cc, (size_t)Cc*Cc };
    int tot = 0;
    for (int i = 0; i < NSEG; ++i) { d.src[i] = srcs[i]; d.dst[i] = dsts[i]; d.n4[i] = (int)(ns[i]/4); tot += d.n4[i]; }
    d.total4 = tot;
    cvt_multi<<<2048, 256, 0, stream>>>(d);
  }
  prep_mem<<<8192, 256, 0, stream>>>((const f4v*)mem, (const f4v*)mem_pos,
                                     (u2v*)kmem_b, (u2v*)vmem_b);

  auto GFP = [&](const float* A0, const float* W0, const float* b0, float* o0,
                 const float* A1, const float* W1, const float* b1, float* o1,
                 int M, int N, int K, bool relu, int zz) {
    dim3 g((N + 63)/64, (M + 63)/64, zz), t(256);
    if (relu) gemm_nt<true ><<<g, t, 0, stream>>>(A0,W0,b0,o0,A1,W1,b1,o1,M,N,K);
    else      gemm_nt<false><<<g, t, 0, stream>>>(A0,W0,b0,o0,A1,W1,b1,o1,M,N,K);
  };

  auto GM = [&](const void* A, const float* A2, const bf16* W, const float* bias,
                void* out, int M, int N, int K, int OM, bool relu) {
    int blocks = (M >> 7) * (N >> 7);
    if (OM == 0) {
      if (relu) gemm_mfma<0,true ,0><<<blocks,256,0,stream>>>(A,A2,W,bias,out,M,N,K);
      else      gemm_mfma<0,false,0><<<blocks,256,0,stream>>>(A,A2,W,bias,out,M,N,K);
    } else if (OM == 1) {
      if (relu) gemm_mfma<0,true ,1><<<blocks,256,0,stream>>>(A,A2,W,bias,out,M,N,K);
      else      gemm_mfma<0,false,1><<<blocks,256,0,stream>>>(A,A2,W,bias,out,M,N,K);
    } else {
      gemm_mfma<0,false,3><<<blocks,256,0,stream>>>(A,A2,W,bias,out,M,N,K);
    }
  };

  // ---- front-end (exact fp32 feeds top-k ordering) ----
  split_subobj<<<(Bb*Nn*Cc + 255)/256, 256, 0, stream>>>(hs, subf, objf);
  GFP(subf, su_w1, su_b1, embh,  objf,  ou_w1, ou_b1, embh2, TT, Cc, Cc, true,  2);
  GFP(embh, su_w2, su_b2, sub_emb, embh2, ou_w2, ou_b2, obj_emb, TT, Cc, Cc, false, 2);
  l2norm_kernel<<<2*TT, 256, 0, stream>>>(sub_emb);   // obj_emb contiguous after sub_emb
  importance_kernel<<<Bb*Nn, 128, 0, stream>>>(sub_emb, obj_emb, imp);
  topk_kernel<<<Bb, 1024, 0, stream>>>(imp, idx);
  gather_pair<<<TT, 256, 0, stream>>>(subf, objf, idx, pair_cat);
  GM(pair_cat, nullptr, pm1b, pm_b1, embh, TT, Cc, 2*Cc, 0, true);
  GM(embh,     nullptr, pm2b, pm_b2, qbuf, TT, Cc, Cc,   0, false);
  boxes_cat_kernel<<<(TT*8 + 255)/256, 256, 0, stream>>>(sub_boxes, obj_boxes, bxc);
  GFP(bxc,  sp_w1, sp_b1, embh, nullptr,nullptr,nullptr,nullptr, TT, Cc, 8,  true,  1);
  GM(embh, nullptr, spw2b, sp_b2, spb, TT, Cc, Cc, 0, false);

  // ---- decoder layers ----
  for (int i = 0; i < Ll; ++i) {
    const bf16* sawL = sawb + (size_t)i*3*Cc*Cc;
    const bf16* cawL = cawb + (size_t)i*3*Cc*Cc;
    const float* sab = sa_in_b + (size_t)i*3*Cc;
    const float* cab = ca_in_b + (size_t)i*3*Cc;

    // self-attention (q_sp = q + sp fused into staging); LN fused into out-proj
    GM(qbuf, spb, sawL, sab, qkvb, TT, 3*Cc, Cc, 1, false);
    attn_sa<<<Bb*Hh, 512, 0, stream>>>(qkvb, attn_o);
    gemm_ln<0><<<TT/16, 512, 0, stream>>>(attn_o, sowb + (size_t)i*Cc*Cc,
        sa_out_b + (size_t)i*Cc, qbuf, n1_g + i*Cc, n1_b + i*Cc, qbuf, TT, Cc,
        nullptr, nullptr);

    // cross-attention: fused K+V+Q projection (barrier-free), flash-decode,
    // combine fused into LN-GEMM
    gemm_kv<<<1074, 256, 0, stream>>>(
        kmem_b, cawL + (size_t)Cc*Cc,   cab + Cc,   khH,
        vmem_b, cawL + (size_t)2*Cc*Cc, cab + 2*Cc, vhH,
        qbuf,   cawL,                   cab,        qhH);
    attn_ca_mfma<<<Bb*Hh*NCH, 256, 0, stream>>>(qhH, khH, vhH, part, mlbuf);
    gemm_ln<2><<<TT/16, 512, 0, stream>>>(nullptr, cowb + (size_t)i*Cc*Cc,
        ca_out_b + (size_t)i*Cc, qbuf, n2_g + i*Cc, n2_b + i*Cc, qbuf, TT, Cc,
        part, mlbuf);

    // FFN (split: bf16 MFMA GEMM + LN-fused second GEMM)
    GM(qbuf, nullptr, l1wb + (size_t)i*Ff*Cc, l1_b + (size_t)i*Ff, ffnb, TT, Ff, Cc, 1, true);
    float* qo = (i == Ll-1) ? (float*)d_out : qbuf;
    gemm_ln<1><<<TT/16, 512, 0, stream>>>(ffnb, l2wb + (size_t)i*Cc*Ff,
        l2_b + (size_t)i*Cc, qbuf, n3_g + i*Cc, n3_b + i*Cc, qo, TT, Ff,
        nullptr, nullptr);
  }
}

// Round 18
// 1581.058 us; speedup vs baseline: 1.0151x; 1.0083x over previous
//
#include <hip/hip_runtime.h>
#include <hip/hip_bf16.h>

#define Bb 32
#define Nn 100
#define Cc 256
#define Mm 4096
#define Ff 2048
#define Ll 6
#define Hh 8
#define DH 32
#define KP 100
#define TT (Bb*KP)
#define LNEPS 1e-5f
#define NCH 8
#define SUBK 128

typedef __hip_bfloat16 bf16;
typedef unsigned short ushort_t;
typedef __attribute__((ext_vector_type(8))) short short8v;
typedef __attribute__((ext_vector_type(4))) float f32x4;
typedef __attribute__((ext_vector_type(4))) float f4v;
typedef __attribute__((ext_vector_type(2))) unsigned u2v;

union FragU { uint2 u2[2]; uint4 u4; short8v s8; };

__device__ __forceinline__ float bfu2f(unsigned short u) {
  union { unsigned u32; float f; } cv; cv.u32 = ((unsigned)u) << 16; return cv.f;
}
__device__ __forceinline__ unsigned short f2bf(float f) {
  union { float f; unsigned u; } c; c.f = f;
  unsigned r = c.u + 0x7FFF + ((c.u >> 16) & 1);
  return (unsigned short)(r >> 16);
}
__device__ __forceinline__ unsigned pack2(float a, float b) {
  return (unsigned)f2bf(a) | ((unsigned)f2bf(b) << 16);
}

// ---------------- fused K+V+Q projection GEMM ----------------
// Barrier-free main loop (direct-from-global MFMA fragments). Three grid
// segments: K (bf16 A), V (bf16 A), Q (fp32 A converted in-register,
// output scaled by 1/sqrt(32)). LDS used only for the coalesced epilogue.
__global__ __launch_bounds__(256) void gemm_kv(
    const bf16* __restrict__ Ak, const bf16* __restrict__ Wk,
    const float* __restrict__ bk, bf16* __restrict__ outK,
    const bf16* __restrict__ Avv, const bf16* __restrict__ Wv,
    const float* __restrict__ bv, bf16* __restrict__ outV,
    const float* __restrict__ Aq, const bf16* __restrict__ Wq,
    const float* __restrict__ bq, bf16* __restrict__ outQ)
{
  __shared__ ushort_t Ct[128*136];
  const int nwgK = ((Bb*Mm) >> 7) * 2;     // 512
  const int nwgQ = (TT >> 7) * 2;          // 50
  const int nwg = 2*nwgK + nwgQ;           // 1074
  const int g = blockIdx.x;
  const int xcd = g & 7, lid = g >> 3;
  const int q8 = nwg >> 3, r8 = nwg & 7;
  int wgid = (xcd < r8 ? xcd*(q8+1) : r8*(q8+1) + (xcd - r8)*q8) + lid;
  int seg;
  const bf16* A = nullptr; const bf16* W; const float* bias; bf16* out;
  if (wgid < nwgK)        { seg = 0; A = Ak;  W = Wk; bias = bk; out = outK; }
  else if (wgid < 2*nwgK) { seg = 1; wgid -= nwgK;   A = Avv; W = Wv; bias = bv; out = outV; }
  else                    { seg = 2; wgid -= 2*nwgK; W = Wq; bias = bq; out = outQ; }
  const int ntile = wgid & 1, mtile = wgid >> 1;
  const int bm = mtile << 7, bn = ntile << 7;
  const int tid = threadIdx.x;
  const int w = tid >> 6, lane = tid & 63;
  const int lr = lane & 15, lg = lane >> 4;
  const int wm = w >> 1, wn = w & 1;

  f32x4 acc[4][4] = {};

  if (seg != 2) {
    #pragma unroll 2
    for (int k0 = 0; k0 < Cc; k0 += 32) {
      FragU a[4], b[4];
      #pragma unroll
      for (int mi = 0; mi < 4; ++mi)
        a[mi].u4 = *(const uint4*)(A + (size_t)(bm + wm*64 + mi*16 + lr)*Cc + k0 + lg*8);
      #pragma unroll
      for (int ni = 0; ni < 4; ++ni)
        b[ni].u4 = *(const uint4*)(W + (size_t)(bn + wn*64 + ni*16 + lr)*Cc + k0 + lg*8);
      #pragma unroll
      for (int ni = 0; ni < 4; ++ni)
        #pragma unroll
        for (int mi = 0; mi < 4; ++mi)
          acc[mi][ni] = __builtin_amdgcn_mfma_f32_16x16x32_bf16(a[mi].s8, b[ni].s8,
                                                                acc[mi][ni], 0, 0, 0);
    }
  } else {
    #pragma unroll 2
    for (int k0 = 0; k0 < Cc; k0 += 32) {
      FragU a[4], b[4];
      #pragma unroll
      for (int mi = 0; mi < 4; ++mi) {
        const float* ap = Aq + (size_t)(bm + wm*64 + mi*16 + lr)*Cc + k0 + lg*8;
        float4 f0 = *(const float4*)ap;
        float4 f1 = *(const float4*)(ap + 4);
        a[mi].u4.x = pack2(f0.x, f0.y); a[mi].u4.y = pack2(f0.z, f0.w);
        a[mi].u4.z = pack2(f1.x, f1.y); a[mi].u4.w = pack2(f1.z, f1.w);
      }
      #pragma unroll
      for (int ni = 0; ni < 4; ++ni)
        b[ni].u4 = *(const uint4*)(W + (size_t)(bn + wn*64 + ni*16 + lr)*Cc + k0 + lg*8);
      #pragma unroll
      for (int ni = 0; ni < 4; ++ni)
        #pragma unroll
        for (int mi = 0; mi < 4; ++mi)
          acc[mi][ni] = __builtin_amdgcn_mfma_f32_16x16x32_bf16(a[mi].s8, b[ni].s8,
                                                                acc[mi][ni], 0, 0, 0);
    }
  }

  // coalesced epilogue: C-tile -> LDS -> 16B stores
  const float scale = (seg == 2) ? 0.17677669529663687f : 1.f;
  #pragma unroll
  for (int ni = 0; ni < 4; ++ni) {
    int col = wn*64 + ni*16 + lr;
    float bvv = bias[bn + col];
    #pragma unroll
    for (int mi = 0; mi < 4; ++mi)
      #pragma unroll
      for (int r = 0; r < 4; ++r) {
        int rowl = wm*64 + mi*16 + lg*4 + r;
        Ct[rowl*136 + col] = f2bf((acc[mi][ni][r] + bvv) * scale);
      }
  }
  __syncthreads();
  for (int u = tid; u < 2048; u += 256) {
    int rowl = u >> 4, sub = u & 15;
    uint4 v = *(const uint4*)&Ct[rowl*136 + sub*8];
    int m = bm + rowl;
    int gcol = bn + sub*8;
    int h = gcol >> 5, dd = gcol & 31;
    if (seg != 2) {
      int bb = m >> 12, mm = m & 4095;
      *(uint4*)(out + (((size_t)bb*Hh + h)*Mm + mm)*DH + dd) = v;
    } else {
      int bb = m / KP, qq = m % KP;
      *(uint4*)(out + (((size_t)bb*Hh + h)*KP + qq)*DH + dd) = v;
    }
  }
}

// ---------------- bf16 MFMA GEMM: out = [A(+A2)] @ W^T + bias ----------------
// OM: 0 fp32 row-major; 1 bf16 row-major; 3 bf16 head-major Q scaled.
template<int AT, bool RELU, int OM>
__global__ __launch_bounds__(256) void gemm_mfma(
    const void* __restrict__ Av, const float* __restrict__ A2,
    const bf16* __restrict__ W, const float* __restrict__ bias,
    void* __restrict__ out, int M, int N, int K)
{
  __shared__ ushort_t SM[2*128*72];
  ushort_t* As = SM;            // [128][72]
  ushort_t* Bs = SM + 128*72;   // [128][72]
  const int mt = M >> 7, nt = N >> 7;
  const int nwg = mt * nt;
  const int g = blockIdx.x;
  const int xcd = g & 7, lid = g >> 3;
  const int q8 = nwg >> 3, r8 = nwg & 7;
  int wgid = (xcd < r8 ? xcd*(q8+1) : r8*(q8+1) + (xcd - r8)*q8) + lid;
  const int ntile = wgid % nt, mtile = wgid / nt;
  const int bm = mtile << 7, bn = ntile << 7;
  const int tid = threadIdx.x;
  const int w = tid >> 6, lane = tid & 63;
  const int lr = lane & 15, lg = lane >> 4;
  const int wm = w >> 1, wn = w & 1;
  const float* Af = (const float*)Av;
  const bf16*  Ab = (const bf16*)Av;

  f32x4 acc[4][4] = {};

  for (int k0 = 0; k0 < K; k0 += 64) {
    __syncthreads();
    #pragma unroll
    for (int i = 0; i < 4; ++i) {
      int linear = i*256 + tid;
      int row = linear >> 3, c8 = linear & 7;
      uint4 packed;
      if (AT == 0) {
        const float* ap = Af + (size_t)(bm+row)*K + k0 + c8*8;
        float4 f0 = *(const float4*)ap;
        float4 f1 = *(const float4*)(ap+4);
        if (A2) {
          const float* ap2 = A2 + (size_t)(bm+row)*K + k0 + c8*8;
          float4 g0 = *(const float4*)ap2;
          float4 g1 = *(const float4*)(ap2+4);
          f0.x += g0.x; f0.y += g0.y; f0.z += g0.z; f0.w += g0.w;
          f1.x += g1.x; f1.y += g1.y; f1.z += g1.z; f1.w += g1.w;
        }
        packed.x = pack2(f0.x, f0.y); packed.y = pack2(f0.z, f0.w);
        packed.z = pack2(f1.x, f1.y); packed.w = pack2(f1.z, f1.w);
      } else {
        packed = *(const uint4*)(Ab + (size_t)(bm+row)*K + k0 + c8*8);
      }
      *(uint4*)&As[row*72 + c8*8] = packed;
      uint4 wb = *(const uint4*)(W + (size_t)(bn+row)*K + k0 + c8*8);
      *(uint4*)&Bs[row*72 + c8*8] = wb;
    }
    __syncthreads();
    #pragma unroll
    for (int kk = 0; kk < 64; kk += 32) {
      FragU a[4];
      #pragma unroll
      for (int mi = 0; mi < 4; ++mi)
        a[mi].u4 = *(const uint4*)&As[(wm*64 + mi*16 + lr)*72 + kk + lg*8];
      #pragma unroll
      for (int ni = 0; ni < 4; ++ni) {
        FragU bfr;
        bfr.u4 = *(const uint4*)&Bs[(wn*64 + ni*16 + lr)*72 + kk + lg*8];
        #pragma unroll
        for (int mi = 0; mi < 4; ++mi)
          acc[mi][ni] = __builtin_amdgcn_mfma_f32_16x16x32_bf16(a[mi].s8, bfr.s8,
                                                                acc[mi][ni], 0, 0, 0);
      }
    }
  }

  #pragma unroll
  for (int ni = 0; ni < 4; ++ni) {
    int col = bn + wn*64 + ni*16 + lr;
    float bv = bias ? bias[col] : 0.f;
    #pragma unroll
    for (int mi = 0; mi < 4; ++mi) {
      #pragma unroll
      for (int r = 0; r < 4; ++r) {
        int m = bm + wm*64 + mi*16 + lg*4 + r;
        float v = acc[mi][ni][r] + bv;
        if (RELU) v = fmaxf(v, 0.f);
        if (OM == 0) {
          ((float*)out)[(size_t)m*N + col] = v;
        } else if (OM == 1) {
          ((bf16*)out)[(size_t)m*N + col] = __float2bfloat16(v);
        } else {
          int bb = m / KP, qq = m % KP;
          int h = col >> 5, dd = col & 31;
          ((bf16*)out)[(((size_t)bb*Hh + h)*KP + qq)*DH + dd] =
              __float2bfloat16(v * 0.17677669529663687f);
        }
      }
    }
  }
}

// ------------- GEMM + bias + residual + LayerNorm fused (N=256 fixed) -------------
// 16x256 tile, 512 thr (8 waves, each 16x32). AT: 0 fp32 A, 1 bf16 A,
// 2 = cross-attn combine: A element = combined flash-decode output (part/ml).
template<int AT>
__global__ __launch_bounds__(512) void gemm_ln(
    const void* __restrict__ Av, const bf16* __restrict__ W,
    const float* __restrict__ bias, const float* __restrict__ resid,
    const float* __restrict__ gamma, const float* __restrict__ beta,
    float* __restrict__ out, int M, int K,
    const bf16* __restrict__ part, const float2* __restrict__ ml)
{
  __shared__ ushort_t As[16][72];
  __shared__ ushort_t Bs[256][72];
  __shared__ float redS[16][8];
  __shared__ float redQ[16][8];
  const int bm = blockIdx.x * 16;
  const int tid = threadIdx.x;
  const int w = tid >> 6, lane = tid & 63;
  const int lr = lane & 15, lg = lane >> 4;
  const float* Af = (const float*)Av;
  const bf16*  Ab = (const bf16*)Av;
  f32x4 acc[2] = {};

  for (int k0 = 0; k0 < K; k0 += 64) {
    __syncthreads();
    if (tid < 128) {
      int row = tid >> 3, c8 = tid & 7;
      uint4 packed;
      if (AT == 0) {
        const float* ap = Af + (size_t)(bm+row)*K + k0 + c8*8;
        float4 f0 = *(const float4*)ap;
        float4 f1 = *(const float4*)(ap+4);
        packed.x = pack2(f0.x, f0.y); packed.y = pack2(f0.z, f0.w);
        packed.z = pack2(f1.x, f1.y); packed.w = pack2(f1.z, f1.w);
      } else if (AT == 1) {
        packed = *(const uint4*)(Ab + (size_t)(bm+row)*K + k0 + c8*8);
      } else {
        int t = bm + row;
        int b = t / KP, q = t % KP;
        int ch0 = k0 + c8*8;
        int h = ch0 >> 5, d0 = ch0 & 31;
        int bh = b*Hh + h;
        float2 mls[NCH];
        float mmax = -1e30f;
        #pragma unroll
        for (int c = 0; c < NCH; ++c) {
          mls[c] = ml[((size_t)bh*NCH + c)*KP + q];
          mmax = fmaxf(mmax, mls[c].x);
        }
        float wc[NCH];
        float L = 0.f;
        #pragma unroll
        for (int c = 0; c < NCH; ++c) {
          wc[c] = __expf(mls[c].x - mmax);
          L += mls[c].y * wc[c];
        }
        float invL = 1.f / L;
        float o[8] = {};
        #pragma unroll
        for (int c = 0; c < NCH; ++c) {
          uint4 pv = *(const uint4*)(part + (((size_t)bh*NCH + c)*KP + q)*DH + d0);
          const ushort_t* pe = (const ushort_t*)&pv;
          #pragma unroll
          for (int e = 0; e < 8; ++e) o[e] += wc[c] * bfu2f(pe[e]);
        }
        packed.x = pack2(o[0]*invL, o[1]*invL);
        packed.y = pack2(o[2]*invL, o[3]*invL);
        packed.z = pack2(o[4]*invL, o[5]*invL);
        packed.w = pack2(o[6]*invL, o[7]*invL);
      }
      *(uint4*)&As[row][c8*8] = packed;
    }
    #pragma unroll
    for (int i = 0; i < 4; ++i) {
      int linear = i*512 + tid;
      int row = linear >> 3, c8 = linear & 7;
      *(uint4*)&Bs[row][c8*8] = *(const uint4*)(W + (size_t)row*K + k0 + c8*8);
    }
    __syncthreads();
    #pragma unroll
    for (int kk = 0; kk < 64; kk += 32) {
      FragU a;
      a.u4 = *(const uint4*)&As[lr][kk + lg*8];
      #pragma unroll
      for (int ni = 0; ni < 2; ++ni) {
        FragU bfr;
        bfr.u4 = *(const uint4*)&Bs[w*32 + ni*16 + lr][kk + lg*8];
        acc[ni] = __builtin_amdgcn_mfma_f32_16x16x32_bf16(a.s8, bfr.s8, acc[ni], 0, 0, 0);
      }
    }
  }

  float x[2][4];
  #pragma unroll
  for (int r = 0; r < 4; ++r) {
    int row = bm + lg*4 + r;
    float s = 0.f, sq = 0.f;
    #pragma unroll
    for (int ni = 0; ni < 2; ++ni) {
      int col = w*32 + ni*16 + lr;
      float v = acc[ni][r] + bias[col] + resid[(size_t)row*Cc + col];
      x[ni][r] = v;
      s += v; sq += v*v;
    }
    #pragma unroll
    for (int m2 = 1; m2 < 16; m2 <<= 1) { s += __shfl_xor(s, m2); sq += __shfl_xor(sq, m2); }
    if (lr == 0) { redS[lg*4 + r][w] = s; redQ[lg*4 + r][w] = sq; }
  }
  __syncthreads();
  #pragma unroll
  for (int r = 0; r < 4; ++r) {
    int lrow = lg*4 + r;
    float ss = 0.f, sq = 0.f;
    #pragma unroll
    for (int j = 0; j < 8; ++j) { ss += redS[lrow][j]; sq += redQ[lrow][j]; }
    float mean = ss * (1.f/Cc);
    float var = sq * (1.f/Cc) - mean*mean;
    float inv = rsqrtf(var + LNEPS);
    #pragma unroll
    for (int ni = 0; ni < 2; ++ni) {
      int col = w*32 + ni*16 + lr;
      out[(size_t)(bm+lrow)*Cc + col] = (x[ni][r] - mean)*inv*gamma[col] + beta[col];
    }
  }
}

// ---- all weight fp32->bf16 conversions in one dispatch ----
#define NSEG 9
struct CvtDesc {
  const float* src[NSEG];
  bf16* dst[NSEG];
  int n4[NSEG];
  int total4;
};
__global__ __launch_bounds__(256) void cvt_multi(CvtDesc d) {
  int stride = gridDim.x * blockDim.x;
  for (int i = blockIdx.x*256 + threadIdx.x; i < d.total4; i += stride) {
    int seg = 0, off = i;
    while (off >= d.n4[seg]) { off -= d.n4[seg]; ++seg; }
    float4 f = *(const float4*)(d.src[seg] + (size_t)off*4);
    uint2 p; p.x = pack2(f.x, f.y); p.y = pack2(f.z, f.w);
    *(uint2*)(d.dst[seg] + (size_t)off*4) = p;
  }
}

// one-time pack: kb = bf16(mem + mem_pos), vb = bf16(mem). Non-temporal.
__global__ __launch_bounds__(256) void prep_mem(const f4v* __restrict__ mem4,
                                                const f4v* __restrict__ pos4,
                                                u2v* __restrict__ kb2,
                                                u2v* __restrict__ vb2) {
  int i = blockIdx.x*256 + threadIdx.x;
  const int stride = 8192*256;
  #pragma unroll
  for (int t = 0; t < 4; ++t) {
    int j = i + t*stride;
    f4v a = __builtin_nontemporal_load(&mem4[j]);
    f4v p = __builtin_nontemporal_load(&pos4[j]);
    u2v vv, kv;
    vv.x = pack2(a.x, a.y); vv.y = pack2(a.z, a.w);
    kv.x = pack2(a.x + p.x, a.y + p.y); kv.y = pack2(a.z + p.z, a.w + p.w);
    __builtin_nontemporal_store(vv, &vb2[j]);
    __builtin_nontemporal_store(kv, &kb2[j]);
  }
}

// ---------------- fp32 GEMM (front-end only), optional z-paired ----------------
template<bool RELU>
__global__ __launch_bounds__(256) void gemm_nt(
    const float* __restrict__ A0, const float* __restrict__ W0,
    const float* __restrict__ b0, float* __restrict__ o0,
    const float* __restrict__ A1, const float* __restrict__ W1,
    const float* __restrict__ b1, float* __restrict__ o1,
    int M, int N, int K)
{
  const float* A = blockIdx.z ? A1 : A0;
  const float* Wt = blockIdx.z ? W1 : W0;
  const float* bias = blockIdx.z ? b1 : b0;
  float* out = blockIdx.z ? o1 : o0;
  __shared__ float As[16][68];
  __shared__ float Ws[16][68];
  const int bm = blockIdx.y * 64, bn = blockIdx.x * 64;
  const int tid = threadIdx.x;
  const int kk = tid & 15, rr = tid >> 4;
  const int tx = tid & 15, ty = tid >> 4;
  float acc[4][4] = {};
  for (int k0 = 0; k0 < K; k0 += 16) {
    #pragma unroll
    for (int p = 0; p < 4; ++p) {
      int m = rr + p*16;
      int row = bm + m;
      float av = 0.f, wv = 0.f;
      bool kin = (k0 + kk) < K;
      if (row < M && kin) av = A[(size_t)row * K + k0 + kk];
      int wrow = bn + m;
      if (wrow < N && kin) wv = Wt[(size_t)wrow * K + k0 + kk];
      As[kk][m] = av;
      Ws[kk][m] = wv;
    }
    __syncthreads();
    #pragma unroll
    for (int q = 0; q < 16; ++q) {
      float a[4], w[4];
      #pragma unroll
      for (int i = 0; i < 4; ++i) a[i] = As[q][ty*4 + i];
      #pragma unroll
      for (int j = 0; j < 4; ++j) w[j] = Ws[q][tx*4 + j];
      #pragma unroll
      for (int i = 0; i < 4; ++i)
        #pragma unroll
        for (int j = 0; j < 4; ++j) acc[i][j] += a[i] * w[j];
    }
    __syncthreads();
  }
  #pragma unroll
  for (int i = 0; i < 4; ++i) {
    int row = bm + ty*4 + i;
    if (row >= M) continue;
    #pragma unroll
    for (int j = 0; j < 4; ++j) {
      int col = bn + tx*4 + j;
      if (col >= N) continue;
      float v = acc[i][j];
      if (bias) v += bias[col];
      if (RELU) v = v > 0.f ? v : 0.f;
      out[(size_t)row*N + col] = v;
    }
  }
}

// ---------------- small kernels ----------------
__global__ void split_subobj(const float* __restrict__ hs,
                             float* __restrict__ subf, float* __restrict__ objf) {
  int i = blockIdx.x*256 + threadIdx.x;
  if (i >= Bb*Nn*Cc) return;
  int c = i % Cc, n = (i / Cc) % Nn, b = i / (Cc*Nn);
  subf[i] = hs[((size_t)b*2*Nn + 2*n    )*Cc + c];
  objf[i] = hs[((size_t)b*2*Nn + 2*n + 1)*Cc + c];
}

__global__ __launch_bounds__(256) void l2norm_kernel(float* __restrict__ x) {
  int t = blockIdx.x, c = threadIdx.x;
  float v = x[(size_t)t*Cc + c];
  __shared__ float red[256];
  red[c] = v*v; __syncthreads();
  for (int s = 128; s > 0; s >>= 1) { if (c < s) red[c] += red[c+s]; __syncthreads(); }
  float scale = 1.f / (sqrtf(red[0]) + 1e-6f);
  x[(size_t)t*Cc + c] = v * scale;
}

__global__ __launch_bounds__(128) void importance_kernel(const float* __restrict__ se,
                                                         const float* __restrict__ oe,
                                                         float* __restrict__ imp) {
  int b = blockIdx.x / Nn, n = blockIdx.x % Nn;
  int m = threadIdx.x;
  if (m >= Nn) return;
  const float* s = se + ((size_t)b*Nn + n)*Cc;
  const float* o = oe + ((size_t)b*Nn + m)*Cc;
  float acc = 0.f;
  for (int c = 0; c < Cc; ++c) acc += s[c] * o[c];
  imp[((size_t)b*Nn + n)*Nn + m] = acc;
}

// ---------------- exact top-k via radix select + bitonic sort ----------------
__global__ __launch_bounds__(1024) void topk_kernel(const float* __restrict__ imp,
                                                    int* __restrict__ idx_out) {
  __shared__ unsigned mu[Nn*Nn];
  __shared__ unsigned hist[256];
  __shared__ unsigned prefix;
  __shared__ int remK;
  __shared__ unsigned long long keys[128];
  __shared__ unsigned tiebuf[256];
  __shared__ unsigned cnt_gt, cnt_tie;
  const int b = blockIdx.x, tid = threadIdx.x;
  const int NN = Nn*Nn;

  for (int i = tid; i < NN; i += 1024) {
    unsigned u = __float_as_uint(imp[(size_t)b*NN + i]);
    mu[i] = (u & 0x80000000u) ? ~u : (u | 0x80000000u);
  }
  if (tid == 0) { prefix = 0u; remK = KP; cnt_gt = 0u; cnt_tie = 0u; }
  __syncthreads();

  for (int shift = 24; shift >= 0; shift -= 8) {
    if (tid < 256) hist[tid] = 0u;
    __syncthreads();
    unsigned pmask = (shift == 24) ? 0u : (0xFFFFFFFFu << (shift + 8));
    unsigned pref = prefix;
    for (int i = tid; i < NN; i += 1024) {
      unsigned v = mu[i];
      if ((v & pmask) == pref) atomicAdd(&hist[(v >> shift) & 0xFFu], 1u);
    }
    __syncthreads();
    if (tid == 0) {
      int rk = remK;
      unsigned sel = 0u;
      for (int bin = 255; bin >= 0; --bin) {
        int c = (int)hist[bin];
        if (c >= rk) { sel = (unsigned)bin; break; }
        rk -= c;
      }
      remK = rk;
      prefix = pref | (sel << shift);
    }
    __syncthreads();
  }

  const unsigned T = prefix;
  const int need = remK;

  for (int i = tid; i < NN; i += 1024) {
    unsigned v = mu[i];
    if (v > T) {
      unsigned p = atomicAdd(&cnt_gt, 1u);
      keys[p] = ((unsigned long long)(~v) << 32) | (unsigned)i;
    } else if (v == T) {
      unsigned p = atomicAdd(&cnt_tie, 1u);
      if (p < 256u) tiebuf[p] = (unsigned)i;
    }
  }
  __syncthreads();
  const unsigned ngt = cnt_gt;
  const unsigned nt_ = cnt_tie < 256u ? cnt_tie : 256u;

  for (int i = tid; i < 256; i += 1024) if (i >= (int)nt_) tiebuf[i] = 0xFFFFFFFFu;
  __syncthreads();
  for (int ksz = 2; ksz <= 256; ksz <<= 1) {
    for (int st = ksz >> 1; st > 0; st >>= 1) {
      if (tid < 128) {
        int i = ((tid & ~(st-1)) << 1) | (tid & (st-1));
        int j = i | st;
        bool up = ((i & ksz) == 0);
        unsigned a = tiebuf[i], c = tiebuf[j];
        if ((a > c) == up) { tiebuf[i] = c; tiebuf[j] = a; }
      }
      __syncthreads();
    }
  }
  for (int t = tid; t < need; t += 1024)
    keys[ngt + t] = ((unsigned long long)(~T) << 32) | tiebuf[t];
  for (int i = tid; i < 128; i += 1024)
    if (i >= KP) keys[i] = 0xFFFFFFFFFFFFFFFFull;
  __syncthreads();

  for (int ksz = 2; ksz <= 128; ksz <<= 1) {
    for (int st = ksz >> 1; st > 0; st >>= 1) {
      if (tid < 64) {
        int i = ((tid & ~(st-1)) << 1) | (tid & (st-1));
        int j = i | st;
        bool up = ((i & ksz) == 0);
        unsigned long long a = keys[i], c = keys[j];
        if ((a > c) == up) { keys[i] = c; keys[j] = a; }
      }
      __syncthreads();
    }
  }
  if (tid < KP) idx_out[b*KP + tid] = (int)(keys[tid] & 0xFFFFFFFFu);
}

__global__ __launch_bounds__(256) void gather_pair(const float* __restrict__ subf,
                                                   const float* __restrict__ objf,
                                                   const int* __restrict__ idx,
                                                   float* __restrict__ pc) {
  int bk = blockIdx.x;
  int b = bk / KP;
  int id = idx[bk];
  int spos = id / Nn, opos = id % Nn;
  const float* s = subf + ((size_t)b*Nn + spos)*Cc;
  const float* o = objf + ((size_t)b*Nn + opos)*Cc;
  float* dst = pc + (size_t)bk * (2*Cc);
  for (int c = threadIdx.x; c < Cc; c += 256) { dst[c] = s[c]; dst[Cc + c] = o[c]; }
}

__global__ void boxes_cat_kernel(const float* __restrict__ sb, const float* __restrict__ ob,
                                 float* __restrict__ out) {
  int i = blockIdx.x*256 + threadIdx.x;
  if (i >= TT*8) return;
  int c = i & 7, bk = i >> 3;
  out[i] = (c < 4) ? sb[bk*4 + c] : ob[bk*4 + (c - 4)];
}

// ---------------- self-attention: 100 keys, one tile (bf16 qkv, bf16 out) ----------------
__global__ __launch_bounds__(512) void attn_sa(const bf16* __restrict__ qkv,
                                               bf16* __restrict__ out) {
  __shared__ float Kt[128][36];
  __shared__ float Vt[128][36];
  __shared__ float Qs[KP][DH];
  __shared__ float Ps[8][128];
  int bh = blockIdx.x; int b = bh >> 3, h = bh & 7;
  int tid = threadIdx.x;
  const float scale = 0.17677669529663687f;
  const size_t base = (size_t)b * KP * (3*Cc);
  for (int i = tid; i < KP*DH; i += 512) {
    int q = i >> 5, d = i & 31;
    Qs[q][d] = __bfloat162float(qkv[base + (size_t)q*(3*Cc) + h*DH + d]) * scale;
  }
  {
    int j = tid >> 2, qc = tid & 3;
    float kf[8], vf[8];
    if (j < KP) {
      uint4 kraw = *(const uint4*)(qkv + base + (size_t)j*(3*Cc) + Cc   + h*DH + qc*8);
      uint4 vraw = *(const uint4*)(qkv + base + (size_t)j*(3*Cc) + 2*Cc + h*DH + qc*8);
      const ushort_t* ks = (const ushort_t*)&kraw;
      const ushort_t* vs = (const ushort_t*)&vraw;
      #pragma unroll
      for (int e = 0; e < 8; ++e) { kf[e] = bfu2f(ks[e]); vf[e] = bfu2f(vs[e]); }
    } else {
      #pragma unroll
      for (int e = 0; e < 8; ++e) { kf[e] = 0.f; vf[e] = 0.f; }
    }
    ((float4*)Kt[j])[qc*2]   = make_float4(kf[0],kf[1],kf[2],kf[3]);
    ((float4*)Kt[j])[qc*2+1] = make_float4(kf[4],kf[5],kf[6],kf[7]);
    ((float4*)Vt[j])[qc*2]   = make_float4(vf[0],vf[1],vf[2],vf[3]);
    ((float4*)Vt[j])[qc*2+1] = make_float4(vf[4],vf[5],vf[6],vf[7]);
  }
  __syncthreads();
  int w = tid >> 6, lane = tid & 63;
  int d = lane & 31, half = lane >> 5;
  for (int q = w; q < KP; q += 8) {
    float s0 = 0.f, s1 = 0.f;
    #pragma unroll
    for (int c = 0; c < 8; ++c) {
      float4 k0 = ((const float4*)Kt[lane])[c];
      float4 k1 = ((const float4*)Kt[lane+64])[c];
      float4 qv = *(const float4*)&Qs[q][c*4];
      s0 += k0.x*qv.x + k0.y*qv.y + k0.z*qv.z + k0.w*qv.w;
      s1 += k1.x*qv.x + k1.y*qv.y + k1.z*qv.z + k1.w*qv.w;
    }
    if (lane >= KP) s0 = -1e30f;
    if (lane + 64 >= KP) s1 = -1e30f;
    float mx = fmaxf(s0, s1);
    #pragma unroll
    for (int m2 = 32; m2 > 0; m2 >>= 1) mx = fmaxf(mx, __shfl_xor(mx, m2));
    float p0 = (lane < KP)      ? expf(s0 - mx) : 0.f;
    float p1 = (lane + 64 < KP) ? expf(s1 - mx) : 0.f;
    float sm = p0 + p1;
    #pragma unroll
    for (int m2 = 32; m2 > 0; m2 >>= 1) sm += __shfl_xor(sm, m2);
    Ps[w][lane] = p0; Ps[w][lane+64] = p1;
    float pv = 0.f;
    for (int s = 0; s < 64; ++s) {
      int j = half*64 + s;
      pv += Ps[w][j] * Vt[j][d];
    }
    pv += __shfl_xor(pv, 32);
    if (lane < 32) out[((size_t)b*KP + q)*Cc + h*DH + d] = __float2bfloat16(pv / sm);
  }
}

// ---------------- cross-attention: MFMA flash-decode, register-resident P ----------------
__global__ __launch_bounds__(256) void attn_ca_mfma(
    const bf16* __restrict__ qhH,   // [bh][100][32] pre-scaled
    const bf16* __restrict__ khH,   // [bh][4096][32]
    const bf16* __restrict__ vhH,   // [bh][4096][32]
    bf16* __restrict__ part,        // [bh][NCH][100][32]
    float2* __restrict__ ml)        // [bh][NCH][100]
{
  __shared__ unsigned short Vs[32][140];
  const int bx = blockIdx.x;
  const int bh = bx >> 3, ch = bx & 7;
  const int tid = threadIdx.x;
  const int w = tid >> 6, lane = tid & 63;
  const int lr = lane & 15, lg = lane >> 4;
  const int k0base = ch * (Mm / NCH);
  const int qt0 = w, qt1 = w + 4;

  FragU qf[2];
  {
    int r0 = qt0*16 + lr;
    qf[0].u4 = *(const uint4*)(qhH + ((size_t)bh*KP + r0)*DH + lg*8);
    int r1 = qt1*16 + lr;
    if (r1 < KP) qf[1].u4 = *(const uint4*)(qhH + ((size_t)bh*KP + r1)*DH + lg*8);
    else         qf[1].u4 = make_uint4(0u,0u,0u,0u);
  }

  f32x4 acc[2][2] = {};
  float mreg[2] = {-1e30f, -1e30f};
  float lreg[2] = {0.f, 0.f};

  const int srcA = (2*(lg & 1))*16 + lr;
  const int srcB = srcA + 16;
  const bool hi_kt = (lg >> 1) != 0;

  for (int sc = 0; sc < (Mm/NCH)/SUBK; ++sc) {
    const int k0 = k0base + sc*SUBK;
    __syncthreads();
    {
      int p2 = tid & 63, c = tid >> 6;
      uint4 v0 = *(const uint4*)(vhH + ((size_t)bh*Mm + k0 + 2*p2    )*DH + c*8);
      uint4 v1 = *(const uint4*)(vhH + ((size_t)bh*Mm + k0 + 2*p2 + 1)*DH + c*8);
      const unsigned short* a0 = (const unsigned short*)&v0;
      const unsigned short* a1 = (const unsigned short*)&v1;
      #pragma unroll
      for (int e = 0; e < 8; ++e) {
        int d = c*8 + e;
        *(unsigned int*)&Vs[d][2*p2] = (unsigned)a0[e] | ((unsigned)a1[e] << 16);
      }
    }
    FragU kf[8];
    #pragma unroll
    for (int kt = 0; kt < 8; ++kt)
      kf[kt].u4 = *(const uint4*)(khH + ((size_t)bh*Mm + k0 + kt*16 + lr)*DH + lg*8);
    __syncthreads();

    #pragma unroll
    for (int j = 0; j < 2; ++j) {
      f32x4 sv[8];
      __builtin_amdgcn_s_setprio(1);
      #pragma unroll
      for (int kt = 0; kt < 8; ++kt) {
        f32x4 z = {0.f, 0.f, 0.f, 0.f};
        sv[kt] = __builtin_amdgcn_mfma_f32_16x16x32_bf16(kf[kt].s8, qf[j].s8, z, 0, 0, 0);
      }
      __builtin_amdgcn_s_setprio(0);
      float mx = -1e30f;
      #pragma unroll
      for (int kt = 0; kt < 8; ++kt)
        mx = fmaxf(mx, fmaxf(fmaxf(sv[kt][0], sv[kt][1]), fmaxf(sv[kt][2], sv[kt][3])));
      mx = fmaxf(mx, __shfl_xor(mx, 16));
      mx = fmaxf(mx, __shfl_xor(mx, 32));
      float newm = fmaxf(mreg[j], mx);
      float resc = __expf(mreg[j] - newm);
      mreg[j] = newm;
      float psum = 0.f;
      unsigned pl[8], ph[8];
      #pragma unroll
      for (int kt = 0; kt < 8; ++kt) {
        float p0 = __expf(sv[kt][0] - newm);
        float p1 = __expf(sv[kt][1] - newm);
        float p2 = __expf(sv[kt][2] - newm);
        float p3 = __expf(sv[kt][3] - newm);
        psum += (p0 + p1) + (p2 + p3);
        pl[kt] = pack2(p0, p1);
        ph[kt] = pack2(p2, p3);
      }
      psum += __shfl_xor(psum, 16);
      psum += __shfl_xor(psum, 32);
      lreg[j] = lreg[j]*resc + psum;
      #pragma unroll
      for (int dt = 0; dt < 2; ++dt)
        #pragma unroll
        for (int r = 0; r < 4; ++r) acc[j][dt][r] *= resc;

      #pragma unroll
      for (int ks = 0; ks < 4; ++ks) {
        unsigned aA = __shfl(pl[2*ks],   srcA), bA = __shfl(pl[2*ks+1], srcA);
        unsigned aB = __shfl(ph[2*ks],   srcA), bB = __shfl(ph[2*ks+1], srcA);
        unsigned cA = __shfl(pl[2*ks],   srcB), dA = __shfl(pl[2*ks+1], srcB);
        unsigned cB = __shfl(ph[2*ks],   srcB), dB = __shfl(ph[2*ks+1], srcB);
        FragU pf;
        pf.u4.x = hi_kt ? bA : aA;
        pf.u4.y = hi_kt ? bB : aB;
        pf.u4.z = hi_kt ? dA : cA;
        pf.u4.w = hi_kt ? dB : cB;
        __builtin_amdgcn_s_setprio(1);
        #pragma unroll
        for (int dt = 0; dt < 2; ++dt) {
          FragU vf;
          vf.u2[0] = *(const uint2*)&Vs[dt*16 + lr][ks*32 + lg*8];
          vf.u2[1] = *(const uint2*)&Vs[dt*16 + lr][ks*32 + lg*8 + 4];
          acc[j][dt] = __builtin_amdgcn_mfma_f32_16x16x32_bf16(vf.s8, pf.s8,
                                                               acc[j][dt], 0, 0, 0);
        }
        __builtin_amdgcn_s_setprio(0);
      }
    }
  }

  #pragma unroll
  for (int j = 0; j < 2; ++j) {
    int q = (j ? qt1 : qt0)*16 + lr;
    if (q < KP) {
      if (lg == 0) ml[((size_t)bh*NCH + ch)*KP + q] = make_float2(mreg[j], lreg[j]);
      #pragma unroll
      for (int dt = 0; dt < 2; ++dt)
        #pragma unroll
        for (int r = 0; r < 4; ++r) {
          int d = dt*16 + lg*4 + r;
          part[(((size_t)bh*NCH + ch)*KP + q)*DH + d] = __float2bfloat16(acc[j][dt][r]);
        }
    }
  }
}

// ---------------- host ----------------
extern "C" void kernel_launch(void* const* d_in, const int* in_sizes, int n_in,
                              void* d_out, int out_size, void* d_ws, size_t ws_size,
                              hipStream_t stream) {
  auto in = [&](int i) { return (const float*)d_in[i]; };
  const float* hs        = in(0);
  const float* mem       = in(1);
  const float* mem_pos   = in(2);
  const float* sub_boxes = in(3);
  const float* obj_boxes = in(4);
  const float* su_w1 = in(5),  *su_b1 = in(6),  *su_w2 = in(7),  *su_b2 = in(8);
  const float* ou_w1 = in(9),  *ou_b1 = in(10), *ou_w2 = in(11), *ou_b2 = in(12);
  const float* pm_w1 = in(13), *pm_b1 = in(14), *pm_w2 = in(15), *pm_b2 = in(16);
  const float* sp_w1 = in(17), *sp_b1 = in(18), *sp_w2 = in(19), *sp_b2 = in(20);
  const float* sa_in_w = in(21),  *sa_in_b = in(22), *sa_out_w = in(23), *sa_out_b = in(24);
  const float* ca_in_w = in(25),  *ca_in_b = in(26), *ca_out_w = in(27), *ca_out_b = in(28);
  const float* l1_w = in(29), *l1_b = in(30), *l2_w = in(31), *l2_b = in(32);
  const float* n1_g = in(33), *n1_b = in(34), *n2_g = in(35), *n2_b = in(36);
  const float* n3_g = in(37), *n3_b = in(38);

  char* wsp = (char*)d_ws;
  auto alloc = [&](size_t bytes) { char* p = wsp; wsp += (bytes + 255) & ~(size_t)255; return p; };
  bf16* khH = (bf16*)alloc((size_t)Bb*Mm*Cc*2);
  bf16* vhH = (bf16*)alloc((size_t)Bb*Mm*Cc*2);
  bf16* kmem_b = (bf16*)alloc((size_t)Bb*Mm*Cc*2);
  bf16* vmem_b = (bf16*)alloc((size_t)Bb*Mm*Cc*2);
  bf16* qhH = (bf16*)alloc((size_t)TT*Cc*2);
  bf16* part = (bf16*)alloc((size_t)Bb*Hh*NCH*KP*DH*2);
  float2* mlbuf = (float2*)alloc((size_t)Bb*Hh*NCH*KP*8);
  bf16* sawb = (bf16*)alloc((size_t)Ll*3*Cc*Cc*2);
  bf16* cawb = (bf16*)alloc((size_t)Ll*3*Cc*Cc*2);
  bf16* sowb = (bf16*)alloc((size_t)Ll*Cc*Cc*2);
  bf16* cowb = (bf16*)alloc((size_t)Ll*Cc*Cc*2);
  bf16* l1wb = (bf16*)alloc((size_t)Ll*Ff*Cc*2);
  bf16* l2wb = (bf16*)alloc((size_t)Ll*Cc*Ff*2);
  bf16* pm1b = (bf16*)alloc((size_t)Cc*2*Cc*2);
  bf16* pm2b = (bf16*)alloc((size_t)Cc*Cc*2);
  bf16* spw2b = (bf16*)alloc((size_t)Cc*Cc*2);
  float* subf    = (float*)alloc((size_t)Bb*Nn*Cc*4);
  float* objf    = (float*)alloc((size_t)Bb*Nn*Cc*4);
  float* sub_emb = (float*)alloc((size_t)Bb*Nn*Cc*4);
  float* obj_emb = (float*)alloc((size_t)Bb*Nn*Cc*4);   // contiguous after sub_emb
  float* embh    = (float*)alloc((size_t)TT*2*Cc*4);
  float* embh2   = (float*)alloc((size_t)TT*Cc*4);
  float* imp     = (float*)alloc((size_t)Bb*Nn*Nn*4);
  int*   idx     = (int*)  alloc((size_t)Bb*KP*4);
  float* pair_cat= (float*)alloc((size_t)TT*2*Cc*4);
  float* bxc     = (float*)alloc((size_t)TT*8*4);
  float* spb     = (float*)alloc((size_t)TT*Cc*4);
  float* qbuf    = (float*)alloc((size_t)TT*Cc*4);
  bf16*  qkvb    = (bf16*)alloc((size_t)TT*3*Cc*2);
  bf16*  attn_ob = (bf16*)alloc((size_t)TT*Cc*2);
  bf16*  ffnb    = (bf16*)alloc((size_t)TT*Ff*2);

  {
    CvtDesc d;
    const float* srcs[NSEG] = { sa_in_w, ca_in_w, sa_out_w, ca_out_w, l1_w, l2_w, pm_w1, pm_w2, sp_w2 };
    bf16* dsts[NSEG] = { sawb, cawb, sowb, cowb, l1wb, l2wb, pm1b, pm2b, spw2b };
    size_t ns[NSEG] = { (size_t)Ll*3*Cc*Cc, (size_t)Ll*3*Cc*Cc, (size_t)Ll*Cc*Cc,
                        (size_t)Ll*Cc*Cc, (size_t)Ll*Ff*Cc, (size_t)Ll*Cc*Ff,
                        (size_t)Cc*2*Cc, (size_t)Cc*Cc, (size_t)Cc*Cc };
    int tot = 0;
    for (int i = 0; i < NSEG; ++i) { d.src[i] = srcs[i]; d.dst[i] = dsts[i]; d.n4[i] = (int)(ns[i]/4); tot += d.n4[i]; }
    d.total4 = tot;
    cvt_multi<<<2048, 256, 0, stream>>>(d);
  }
  prep_mem<<<8192, 256, 0, stream>>>((const f4v*)mem, (const f4v*)mem_pos,
                                     (u2v*)kmem_b, (u2v*)vmem_b);

  auto GFP = [&](const float* A0, const float* W0, const float* b0, float* o0,
                 const float* A1, const float* W1, const float* b1, float* o1,
                 int M, int N, int K, bool relu, int zz) {
    dim3 g((N + 63)/64, (M + 63)/64, zz), t(256);
    if (relu) gemm_nt<true ><<<g, t, 0, stream>>>(A0,W0,b0,o0,A1,W1,b1,o1,M,N,K);
    else      gemm_nt<false><<<g, t, 0, stream>>>(A0,W0,b0,o0,A1,W1,b1,o1,M,N,K);
  };

  auto GM = [&](const void* A, const float* A2, const bf16* W, const float* bias,
                void* out, int M, int N, int K, int OM, bool relu) {
    int blocks = (M >> 7) * (N >> 7);
    if (OM == 0) {
      if (relu) gemm_mfma<0,true ,0><<<blocks,256,0,stream>>>(A,A2,W,bias,out,M,N,K);
      else      gemm_mfma<0,false,0><<<blocks,256,0,stream>>>(A,A2,W,bias,out,M,N,K);
    } else if (OM == 1) {
      if (relu) gemm_mfma<0,true ,1><<<blocks,256,0,stream>>>(A,A2,W,bias,out,M,N,K);
      else      gemm_mfma<0,false,1><<<blocks,256,0,stream>>>(A,A2,W,bias,out,M,N,K);
    } else {
      gemm_mfma<0,false,3><<<blocks,256,0,stream>>>(A,A2,W,bias,out,M,N,K);
    }
  };

  // ---- front-end (exact fp32 feeds top-k ordering) ----
  split_subobj<<<(Bb*Nn*Cc + 255)/256, 256, 0, stream>>>(hs, subf, objf);
  GFP(subf, su_w1, su_b1, embh,  objf,  ou_w1, ou_b1, embh2, TT, Cc, Cc, true,  2);
  GFP(embh, su_w2, su_b2, sub_emb, embh2, ou_w2, ou_b2, obj_emb, TT, Cc, Cc, false, 2);
  l2norm_kernel<<<2*TT, 256, 0, stream>>>(sub_emb);   // obj_emb contiguous after sub_emb
  importance_kernel<<<Bb*Nn, 128, 0, stream>>>(sub_emb, obj_emb, imp);
  topk_kernel<<<Bb, 1024, 0, stream>>>(imp, idx);
  gather_pair<<<TT, 256, 0, stream>>>(subf, objf, idx, pair_cat);
  GM(pair_cat, nullptr, pm1b, pm_b1, embh, TT, Cc, 2*Cc, 0, true);
  GM(embh,     nullptr, pm2b, pm_b2, qbuf, TT, Cc, Cc,   0, false);
  boxes_cat_kernel<<<(TT*8 + 255)/256, 256, 0, stream>>>(sub_boxes, obj_boxes, bxc);
  GFP(bxc,  sp_w1, sp_b1, embh, nullptr,nullptr,nullptr,nullptr, TT, Cc, 8,  true,  1);
  GM(embh, nullptr, spw2b, sp_b2, spb, TT, Cc, Cc, 0, false);

  // ---- decoder layers ----
  for (int i = 0; i < Ll; ++i) {
    const bf16* sawL = sawb + (size_t)i*3*Cc*Cc;
    const bf16* cawL = cawb + (size_t)i*3*Cc*Cc;
    const float* sab = sa_in_b + (size_t)i*3*Cc;
    const float* cab = ca_in_b + (size_t)i*3*Cc;

    // self-attention (q_sp = q + sp fused into staging); LN fused into out-proj
    GM(qbuf, spb, sawL, sab, qkvb, TT, 3*Cc, Cc, 1, false);
    attn_sa<<<Bb*Hh, 512, 0, stream>>>(qkvb, attn_ob);
    gemm_ln<1><<<TT/16, 512, 0, stream>>>(attn_ob, sowb + (size_t)i*Cc*Cc,
        sa_out_b + (size_t)i*Cc, qbuf, n1_g + i*Cc, n1_b + i*Cc, qbuf, TT, Cc,
        nullptr, nullptr);

    // cross-attention: fused K+V+Q projection (barrier-free), flash-decode,
    // combine fused into LN-GEMM
    gemm_kv<<<1074, 256, 0, stream>>>(
        kmem_b, cawL + (size_t)Cc*Cc,   cab + Cc,   khH,
        vmem_b, cawL + (size_t)2*Cc*Cc, cab + 2*Cc, vhH,
        qbuf,   cawL,                   cab,        qhH);
    attn_ca_mfma<<<Bb*Hh*NCH, 256, 0, stream>>>(qhH, khH, vhH, part, mlbuf);
    gemm_ln<2><<<TT/16, 512, 0, stream>>>(nullptr, cowb + (size_t)i*Cc*Cc,
        ca_out_b + (size_t)i*Cc, qbuf, n2_g + i*Cc, n2_b + i*Cc, qbuf, TT, Cc,
        part, mlbuf);

    // FFN (split: bf16 MFMA GEMM + LN-fused second GEMM)
    GM(qbuf, nullptr, l1wb + (size_t)i*Ff*Cc, l1_b + (size_t)i*Ff, ffnb, TT, Ff, Cc, 1, true);
    float* qo = (i == Ll-1) ? (float*)d_out : qbuf;
    gemm_ln<1><<<TT/16, 512, 0, stream>>>(ffnb, l2wb + (size_t)i*Cc*Ff,
        l2_b + (size_t)i*Cc, qbuf, n3_g + i*Cc, n3_b + i*Cc, qo, TT, Ff,
        nullptr, nullptr);
  }
}